// Round 14
// baseline (340.421 us; speedup 1.0000x reference)
//
#include <hip/hip_runtime.h>
#include <hip/hip_bf16.h>

// ---------------------------------------------------------------------------
// Problem constants
#define B_   4
#define SQ_  2048
#define SK_  2048
#define D_   1024
#define H_   16
#define HD_  64

#define LOG2E 1.4426950408889634f

typedef __bf16 bf16_t;
typedef bf16_t bf16x8 __attribute__((ext_vector_type(8)));
typedef bf16_t bf16x4 __attribute__((ext_vector_type(4)));
typedef float  f32x4  __attribute__((ext_vector_type(4)));
typedef int    i32x4  __attribute__((ext_vector_type(4)));
typedef unsigned u32x2 __attribute__((ext_vector_type(2)));

// MFMA 16x16x32 bf16 verified layouts (learn_hip m89/m91):
//   A operand: lane l, elem j -> A[m = l&15][k = (l>>4)*8 + j]
//   B operand: lane l, elem j -> B[k = (l>>4)*8 + j][n = l&15]
//   C/D:       lane l, reg  r -> D[m = (l>>4)*4 + r][n = l&15]

// Tiled K layout (per (b,h,kt) 64x64 tile): elem(kp,d) at
//   kp*64 + ((d>>3) ^ (kp&7))*8 + (d&7)
// Tiled V layout: column-permuted to match P-frag k-perm:
//   col v -> chunk = ((v>>5)&1)*4 + ((v>>2)&3), j = ((v>>4)&1)*4 + (v&3)
//   elem(d,v) at d*64 + ((chunk ^ (d&7))*8) + j

__device__ __forceinline__ void gll16(const bf16_t* g, bf16_t* l) {
    __builtin_amdgcn_global_load_lds(
        (const __attribute__((address_space(1))) unsigned int*)g,
        (__attribute__((address_space(3))) unsigned int*)l, 16, 0, 0);
}

// ---------------------------------------------------------------------------
// fp32 -> bf16 convert prepass. y selects source; dst = d + y*n.
__global__ __launch_bounds__(256) void cvt_bf16(
    const float* __restrict__ p0, const float* __restrict__ p1,
    const float* __restrict__ p2, const float* __restrict__ p3,
    bf16_t* __restrict__ d, int n)
{
    int y = blockIdx.y;
    const float* s = (y == 0) ? p0 : (y == 1) ? p1 : (y == 2) ? p2 : p3;
    int i = (blockIdx.x * 256 + threadIdx.x) * 8;
    f32x4 a = *(const f32x4*)(s + i);
    f32x4 b = *(const f32x4*)(s + i + 4);
    bf16x8 o;
    #pragma unroll
    for (int j = 0; j < 4; j++) { o[j] = (bf16_t)a[j]; o[4 + j] = (bf16_t)b[j]; }
    *(bf16x8*)(d + (size_t)y * n + i) = o;
}

// ---------------------------------------------------------------------------
// bf16 GEMM (m97 structure): C = A @ B^T, 128x128 tile, BK=32,
// global_load_lds staging into XOR-swizzled LDS, double-buffered.
__global__ __launch_bounds__(256) void gemm_qkv(
    const bf16_t* __restrict__ xb,   // [3][8192][1024]
    const bf16_t* __restrict__ wb,   // [4][1024][1024] (0..2 used)
    const float* __restrict__ bq, const float* __restrict__ bk, const float* __restrict__ bv,
    bf16_t* __restrict__ oq, bf16_t* __restrict__ ok, bf16_t* __restrict__ ov)
{
    __shared__ __align__(16) bf16_t lA[2][4096];
    __shared__ __align__(16) bf16_t lB[2][4096];

    int z = blockIdx.z;
    const bf16_t* A = xb + (size_t)z * 8192 * 1024;
    const bf16_t* Bm = wb + (size_t)z * 1024 * 1024;
    const float* bias = (z == 0) ? bq : (z == 1) ? bk : bv;
    bf16_t* out = (z == 0) ? oq : (z == 1) ? ok : ov;

    int tid = threadIdx.x;
    int w = tid >> 6, l = tid & 63, lr = l & 15, lg = l >> 4;
    int m0 = blockIdx.x * 128, n0 = blockIdx.y * 128;
    int wm = (w >> 1) * 64, wn = (w & 1) * 64;

    f32x4 zero4 = {0.f, 0.f, 0.f, 0.f};
    f32x4 acc[4][4];
    #pragma unroll
    for (int i = 0; i < 4; i++)
        #pragma unroll
        for (int j = 0; j < 4; j++) acc[i][j] = zero4;

    int s0 = tid, s1 = 256 + tid;
    int r0 = s0 >> 2, c0 = s0 & 3, r1 = s1 >> 2, c1 = s1 & 3;
    const bf16_t* a0 = A + (size_t)(m0 + r0) * 1024 + ((c0 ^ ((r0 >> 1) & 3)) * 8);
    const bf16_t* a1 = A + (size_t)(m0 + r1) * 1024 + ((c1 ^ ((r1 >> 1) & 3)) * 8);
    const bf16_t* b0 = Bm + (size_t)(n0 + r0) * 1024 + ((c0 ^ ((r0 >> 1) & 3)) * 8);
    const bf16_t* b1 = Bm + (size_t)(n0 + r1) * 1024 + ((c1 ^ ((r1 >> 1) & 3)) * 8);

    auto stage = [&](int buf, int kt) {
        gll16(a0 + kt * 32, &lA[buf][s0 * 8]);
        gll16(a1 + kt * 32, &lA[buf][s1 * 8]);
        gll16(b0 + kt * 32, &lB[buf][s0 * 8]);
        gll16(b1 + kt * 32, &lB[buf][s1 * 8]);
    };

    stage(0, 0);
    int buf = 0;
    #pragma unroll 1
    for (int kt = 0; kt < 32; ++kt) {
        __syncthreads();                 // drains stage(kt)
        if (kt + 1 < 32) stage(buf ^ 1, kt + 1);
        bf16x8 af[4], bfr[4];
        #pragma unroll
        for (int i = 0; i < 4; i++) {
            int ra = wm + i * 16 + lr;
            af[i] = *(const bf16x8*)&lA[buf][ra * 32 + ((lg ^ ((ra >> 1) & 3)) * 8)];
            int rb = wn + i * 16 + lr;
            bfr[i] = *(const bf16x8*)&lB[buf][rb * 32 + ((lg ^ ((rb >> 1) & 3)) * 8)];
        }
        #pragma unroll
        for (int mi = 0; mi < 4; mi++)
            #pragma unroll
            for (int ni = 0; ni < 4; ni++)
                acc[mi][ni] = __builtin_amdgcn_mfma_f32_16x16x32_bf16(af[mi], bfr[ni], acc[mi][ni], 0, 0, 0);
        buf ^= 1;
    }

    #pragma unroll
    for (int mi = 0; mi < 4; mi++) {
        int row = m0 + wm + mi * 16 + lg * 4;       // row = b*2048 + s(or kpos)
        int bb_ = row >> 11;
        int s   = row & 2047;
        #pragma unroll
        for (int ni = 0; ni < 4; ni++) {
            int col = n0 + wn + ni * 16 + lr;       // col = h*64 + d
            int hh = col >> 6, d6 = col & 63;
            float bval = bias[col];
            if (z == 0) {
                // Q pre-scaled by 0.125*log2e so attn can use exp2 directly
                size_t obase = (((size_t)bb_ * H_ + hh) * SQ_ + s) * HD_ + d6;
                #pragma unroll
                for (int r = 0; r < 4; r++)
                    out[obase + (size_t)r * HD_] =
                        (bf16_t)((acc[mi][ni][r] + bval) * (0.125f * LOG2E));
            } else if (z == 1) {
                int kt = s >> 6, kpb = s & 63;
                size_t tb = (((size_t)bb_ * H_ + hh) * 32 + kt) * 4096;
                #pragma unroll
                for (int r = 0; r < 4; r++) {
                    int kp = kpb + r;
                    out[tb + (size_t)kp * 64 + (((d6 >> 3) ^ (kp & 7)) * 8) + (d6 & 7)] =
                        (bf16_t)(acc[mi][ni][r] + bval);
                }
            } else {
                int kt = s >> 6, kpb = s & 63;
                int chunk = ((kpb >> 5) & 1) * 4 + ((kpb >> 2) & 3);
                int jb    = ((kpb >> 4) & 1) * 4;
                size_t tb = (((size_t)bb_ * H_ + hh) * 32 + kt) * 4096;
                bf16x4 o4;
                #pragma unroll
                for (int r = 0; r < 4; r++) o4[r] = (bf16_t)(acc[mi][ni][r] + bval);
                *(bf16x4*)(out + tb + (size_t)d6 * 64 + ((chunk ^ (d6 & 7)) * 8) + jb) = o4;
            }
        }
    }
}

// ---------------------------------------------------------------------------
// O projection: tmp = ctx(bf16) @ Wo^T + bo + resid(fp32), fp32 out.
__global__ __launch_bounds__(256) void gemm_out(
    const bf16_t* __restrict__ A, const bf16_t* __restrict__ Bm,
    const float* __restrict__ bias, const float* __restrict__ resid,
    float* __restrict__ out)
{
    __shared__ __align__(16) bf16_t lA[2][4096];
    __shared__ __align__(16) bf16_t lB[2][4096];

    int tid = threadIdx.x;
    int w = tid >> 6, l = tid & 63, lr = l & 15, lg = l >> 4;
    int m0 = blockIdx.x * 128, n0 = blockIdx.y * 128;
    int wm = (w >> 1) * 64, wn = (w & 1) * 64;

    f32x4 zero4 = {0.f, 0.f, 0.f, 0.f};
    f32x4 acc[4][4];
    #pragma unroll
    for (int i = 0; i < 4; i++)
        #pragma unroll
        for (int j = 0; j < 4; j++) acc[i][j] = zero4;

    int s0 = tid, s1 = 256 + tid;
    int r0 = s0 >> 2, c0 = s0 & 3, r1 = s1 >> 2, c1 = s1 & 3;
    const bf16_t* a0 = A + (size_t)(m0 + r0) * 1024 + ((c0 ^ ((r0 >> 1) & 3)) * 8);
    const bf16_t* a1 = A + (size_t)(m0 + r1) * 1024 + ((c1 ^ ((r1 >> 1) & 3)) * 8);
    const bf16_t* b0 = Bm + (size_t)(n0 + r0) * 1024 + ((c0 ^ ((r0 >> 1) & 3)) * 8);
    const bf16_t* b1 = Bm + (size_t)(n0 + r1) * 1024 + ((c1 ^ ((r1 >> 1) & 3)) * 8);

    auto stage = [&](int buf, int kt) {
        gll16(a0 + kt * 32, &lA[buf][s0 * 8]);
        gll16(a1 + kt * 32, &lA[buf][s1 * 8]);
        gll16(b0 + kt * 32, &lB[buf][s0 * 8]);
        gll16(b1 + kt * 32, &lB[buf][s1 * 8]);
    };

    stage(0, 0);
    int buf = 0;
    #pragma unroll 1
    for (int kt = 0; kt < 32; ++kt) {
        __syncthreads();
        if (kt + 1 < 32) stage(buf ^ 1, kt + 1);
        bf16x8 af[4], bfr[4];
        #pragma unroll
        for (int i = 0; i < 4; i++) {
            int ra = wm + i * 16 + lr;
            af[i] = *(const bf16x8*)&lA[buf][ra * 32 + ((lg ^ ((ra >> 1) & 3)) * 8)];
            int rb = wn + i * 16 + lr;
            bfr[i] = *(const bf16x8*)&lB[buf][rb * 32 + ((lg ^ ((rb >> 1) & 3)) * 8)];
        }
        #pragma unroll
        for (int mi = 0; mi < 4; mi++)
            #pragma unroll
            for (int ni = 0; ni < 4; ni++)
                acc[mi][ni] = __builtin_amdgcn_mfma_f32_16x16x32_bf16(af[mi], bfr[ni], acc[mi][ni], 0, 0, 0);
        buf ^= 1;
    }

    #pragma unroll
    for (int mi = 0; mi < 4; mi++) {
        int row = m0 + wm + mi * 16 + lg * 4;
        #pragma unroll
        for (int ni = 0; ni < 4; ni++) {
            int col = n0 + wn + ni * 16 + lr;
            float bval = bias[col];
            #pragma unroll
            for (int r = 0; r < 4; r++) {
                size_t o = (size_t)(row + r) * D_ + col;
                out[o] = acc[mi][ni][r] + bval + resid[o];
            }
        }
    }
}

// ---------------------------------------------------------------------------
// Flash attention: (b,h,qt-of-128) per block, 4 waves x 32 q-rows (2 q-sets).
// r10 structure (known-good): single __syncthreads per tile; stage(t+1)
// issued at top of body (full-body cover before the barrier drain); bias
// loaded in-body via compiler-tracked loads. NEW (pure HIP, no asm loads):
//   - denominator via MFMA ones-trick: lacc = mfma(ones, P, lacc) gives
//     colsum(P) per q-lane, accumulated over tiles -> no per-tile scalar
//     reduction chain, no final shfl reduction.
//   - exp2 path: Q pre-scaled by 0.125*log2e; p = exp2(fma(b_mask, log2e, s))
__global__ __launch_bounds__(256) void attn_kernel(
    const bf16_t* __restrict__ qg, const bf16_t* __restrict__ kgt,
    const bf16_t* __restrict__ vgt, const float* __restrict__ bias,
    const int* __restrict__ mask, bf16_t* __restrict__ ctx)
{
    __shared__ __align__(16) bf16_t ksh[2][4096];
    __shared__ __align__(16) bf16_t vsh[2][4096];
    __shared__ __align__(8) unsigned char mlds[256];   // 2048 mask bits

    // Swizzle: the 4 batch-siblings of one (h,qt) share x mod 8 -> same XCD L2
    int x = blockIdx.x;              // 1024 blocks
    int g8 = x & 7;
    int rest = x >> 3;               // 0..127
    int b  = rest & 3;
    int tt = ((rest >> 2) << 3) | g8;   // 0..255
    int h  = tt >> 4;
    int qt = tt & 15;

    int tid = threadIdx.x;
    int w   = tid >> 6;
    int l   = tid & 63;
    int q16 = l & 15;
    int g   = l >> 4;
    int g4  = g * 4;

    int qrow0 = qt * 128 + w * 16 + q16;
    int qrow1 = qrow0 + 64;
    const bf16_t* qbase = qg + ((size_t)b * H_ + h) * SQ_ * HD_;
    bf16x8 qf00 = *(const bf16x8*)(qbase + (size_t)qrow0 * HD_ + g * 8);
    bf16x8 qf01 = *(const bf16x8*)(qbase + (size_t)qrow0 * HD_ + 32 + g * 8);
    bf16x8 qf10 = *(const bf16x8*)(qbase + (size_t)qrow1 * HD_ + g * 8);
    bf16x8 qf11 = *(const bf16x8*)(qbase + (size_t)qrow1 * HD_ + 32 + g * 8);

    const bf16_t* kt_base = kgt + ((size_t)b * H_ + h) * 32 * 4096;
    const bf16_t* vt_base = vgt + ((size_t)b * H_ + h) * 32 * 4096;
    const float* bias_row0 = bias + ((size_t)h * SQ_ + qrow0) * SK_;
    const float* bias_row1 = bias + ((size_t)h * SQ_ + qrow1) * SK_;

    f32x4 zero4 = {0.f, 0.f, 0.f, 0.f};
    f32x4 oacc0[4], oacc1[4];
    #pragma unroll
    for (int i = 0; i < 4; i++) { oacc0[i] = zero4; oacc1[i] = zero4; }
    f32x4 lacc0 = zero4, lacc1 = zero4;   // ones-trick denominator accumulators

    bf16x8 ones;
    #pragma unroll
    for (int i = 0; i < 8; i++) ones[i] = (bf16_t)1.0f;

    auto stage = [&](int buf, int t) {   // 4 gll16 per thread
        const bf16_t* ks = kt_base + (size_t)t * 4096 + tid * 8;
        const bf16_t* vs = vt_base + (size_t)t * 4096 + tid * 8;
        gll16(ks,        &ksh[buf][tid * 8]);
        gll16(ks + 2048, &ksh[buf][2048 + tid * 8]);
        gll16(vs,        &vsh[buf][tid * 8]);
        gll16(vs + 2048, &vsh[buf][2048 + tid * 8]);
    };

    // ---- prologue ----
    stage(0, 0);
    {
        const int* mp = mask + (size_t)b * SK_ + tid * 8;
        i32x4 u0 = *(const i32x4*)mp;
        i32x4 u1 = *(const i32x4*)(mp + 4);
        unsigned by = 0;
        #pragma unroll
        for (int j = 0; j < 4; j++) by |= (u0[j] != 0 ? 1u : 0u) << j;
        #pragma unroll
        for (int j = 0; j < 4; j++) by |= (u1[j] != 0 ? 1u : 0u) << (4 + j);
        mlds[tid] = (unsigned char)by;
    }
    __syncthreads();     // mlds visible; tile 0 staged

    #pragma unroll 1
    for (int t = 0; t < 32; ++t) {
        int buf = t & 1;
        // ---- stage next tile FIRST (full body of cover before the drain) ----
        if (t + 1 < 32) stage(buf ^ 1, t + 1);

        // ---- bias + mask issued early (latency hides under QK^T) ----
        f32x4 bb0[4], bb1[4];
        const float* bp0 = bias_row0 + t * 64 + g4;
        const float* bp1 = bias_row1 + t * 64 + g4;
        #pragma unroll
        for (int ni = 0; ni < 4; ni++) {
            bb0[ni] = *(const f32x4*)(bp0 + ni * 16);
            bb1[ni] = *(const f32x4*)(bp1 + ni * 16);
        }
        u32x2 mm = *(const u32x2*)&mlds[t * 8];
        unsigned lo = mm[0], hi = mm[1];

        // ---- S^T = K Q^T, both q-sets share K frags ----
        f32x4 s0[4], s1[4];
        __builtin_amdgcn_s_setprio(1);
        #pragma unroll
        for (int ni = 0; ni < 4; ni++) {
            int krow = ni * 16 + q16;
            const bf16_t* kr = &ksh[buf][0] + krow * 64;
            bf16x8 kf0 = *(const bf16x8*)(kr + ((g       ^ (krow & 7)) * 8));
            bf16x8 kf1 = *(const bf16x8*)(kr + (((4 + g) ^ (krow & 7)) * 8));
            s0[ni] = zero4; s1[ni] = zero4;
            s0[ni] = __builtin_amdgcn_mfma_f32_16x16x32_bf16(kf0, qf00, s0[ni], 0, 0, 0);
            s0[ni] = __builtin_amdgcn_mfma_f32_16x16x32_bf16(kf1, qf01, s0[ni], 0, 0, 0);
            s1[ni] = __builtin_amdgcn_mfma_f32_16x16x32_bf16(kf0, qf10, s1[ni], 0, 0, 0);
            s1[ni] = __builtin_amdgcn_mfma_f32_16x16x32_bf16(kf1, qf11, s1[ni], 0, 0, 0);
        }
        __builtin_amdgcn_s_setprio(0);

        unsigned n0_ = (lo >> g4) & 0xF;
        unsigned n1_ = (lo >> (16 + g4)) & 0xF;
        unsigned n2_ = (hi >> g4) & 0xF;
        unsigned n3_ = (hi >> (16 + g4)) & 0xF;

        bf16x8 pA0, pA1, pB0, pB1;
        #pragma unroll
        for (int r = 0; r < 4; r++) {
            float b00 = ((n0_ >> r) & 1) ? bb0[0][r] : -30000.f;
            float b01 = ((n1_ >> r) & 1) ? bb0[1][r] : -30000.f;
            float b02 = ((n2_ >> r) & 1) ? bb0[2][r] : -30000.f;
            float b03 = ((n3_ >> r) & 1) ? bb0[3][r] : -30000.f;
            pA0[r]     = (bf16_t)exp2f(fmaf(b00, LOG2E, s0[0][r]));
            pA0[4 + r] = (bf16_t)exp2f(fmaf(b01, LOG2E, s0[1][r]));
            pA1[r]     = (bf16_t)exp2f(fmaf(b02, LOG2E, s0[2][r]));
            pA1[4 + r] = (bf16_t)exp2f(fmaf(b03, LOG2E, s0[3][r]));
            float b10 = ((n0_ >> r) & 1) ? bb1[0][r] : -30000.f;
            float b11 = ((n1_ >> r) & 1) ? bb1[1][r] : -30000.f;
            float b12 = ((n2_ >> r) & 1) ? bb1[2][r] : -30000.f;
            float b13 = ((n3_ >> r) & 1) ? bb1[3][r] : -30000.f;
            pB0[r]     = (bf16_t)exp2f(fmaf(b10, LOG2E, s1[0][r]));
            pB0[4 + r] = (bf16_t)exp2f(fmaf(b11, LOG2E, s1[1][r]));
            pB1[r]     = (bf16_t)exp2f(fmaf(b12, LOG2E, s1[2][r]));
            pB1[4 + r] = (bf16_t)exp2f(fmaf(b13, LOG2E, s1[3][r]));
        }

        // ---- O^T += V^T P, denominators += ones^T P (colsum) ----
        __builtin_amdgcn_s_setprio(1);
        lacc0 = __builtin_amdgcn_mfma_f32_16x16x32_bf16(ones, pA0, lacc0, 0, 0, 0);
        lacc0 = __builtin_amdgcn_mfma_f32_16x16x32_bf16(ones, pA1, lacc0, 0, 0, 0);
        lacc1 = __builtin_amdgcn_mfma_f32_16x16x32_bf16(ones, pB0, lacc1, 0, 0, 0);
        lacc1 = __builtin_amdgcn_mfma_f32_16x16x32_bf16(ones, pB1, lacc1, 0, 0, 0);
        #pragma unroll
        for (int nd = 0; nd < 4; nd++) {
            int vrow = nd * 16 + q16;
            const bf16_t* vr = &vsh[buf][0] + vrow * 64;
            bf16x8 vf0 = *(const bf16x8*)(vr + ((g       ^ (vrow & 7)) * 8));
            bf16x8 vf1 = *(const bf16x8*)(vr + (((4 + g) ^ (vrow & 7)) * 8));
            oacc0[nd] = __builtin_amdgcn_mfma_f32_16x16x32_bf16(vf0, pA0, oacc0[nd], 0, 0, 0);
            oacc0[nd] = __builtin_amdgcn_mfma_f32_16x16x32_bf16(vf1, pA1, oacc0[nd], 0, 0, 0);
            oacc1[nd] = __builtin_amdgcn_mfma_f32_16x16x32_bf16(vf0, pB0, oacc1[nd], 0, 0, 0);
            oacc1[nd] = __builtin_amdgcn_mfma_f32_16x16x32_bf16(vf1, pB1, oacc1[nd], 0, 0, 0);
        }
        __builtin_amdgcn_s_setprio(0);

        // ---- single barrier per tile: drains stage(t+1), resolves WAR ----
        __syncthreads();
    }

    // ---- denominators: lacc[m][q16] = colsum P, identical across m ----
    float l_r0 = lacc0[0];
    float l_r1 = lacc1[0];
    float inv0 = (l_r0 > 0.f) ? 1.0f / l_r0 : 0.f;
    float inv1 = (l_r1 > 0.f) ? 1.0f / l_r1 : 0.f;

    bf16_t* cp0 = ctx + ((size_t)b * SQ_ + qrow0) * D_ + (size_t)h * HD_;
    bf16_t* cp1 = ctx + ((size_t)b * SQ_ + qrow1) * D_ + (size_t)h * HD_;
    #pragma unroll
    for (int nd = 0; nd < 4; nd++) {
        bf16x4 o4, o5;
        #pragma unroll
        for (int r = 0; r < 4; r++) {
            o4[r] = (bf16_t)(oacc0[nd][r] * inv0);
            o5[r] = (bf16_t)(oacc1[nd][r] * inv1);
        }
        *(bf16x4*)(cp0 + nd * 16 + g4) = o4;
        *(bf16x4*)(cp1 + nd * 16 + g4) = o5;
    }
}

// ---------------------------------------------------------------------------
// LayerNorm over D=1024, one block (256 threads) per row, fp32 in/out
__global__ __launch_bounds__(256) void ln_kernel(
    const float* __restrict__ x, const float* __restrict__ gamma,
    const float* __restrict__ beta, float* __restrict__ out)
{
    int row = blockIdx.x;
    int t = threadIdx.x;
    const float* src = x + (size_t)row * D_;
    f32x4 v = *(const f32x4*)(src + t * 4);
    float s  = v[0] + v[1] + v[2] + v[3];
    float s2 = v[0] * v[0] + v[1] * v[1] + v[2] * v[2] + v[3] * v[3];
    #pragma unroll
    for (int off = 32; off > 0; off >>= 1) {
        s  += __shfl_down(s, off);
        s2 += __shfl_down(s2, off);
    }
    __shared__ float red[8];
    int w = t >> 6, l = t & 63;
    if (l == 0) { red[w] = s; red[4 + w] = s2; }
    __syncthreads();
    if (t == 0) {
        red[0] = red[0] + red[1] + red[2] + red[3];
        red[4] = red[4] + red[5] + red[6] + red[7];
    }
    __syncthreads();
    float mu  = red[0] * (1.0f / D_);
    float var = red[4] * (1.0f / D_) - mu * mu;
    float rstd = rsqrtf(var + 1e-5f);
    f32x4 g  = *(const f32x4*)(gamma + t * 4);
    f32x4 be = *(const f32x4*)(beta + t * 4);
    f32x4 o;
    #pragma unroll
    for (int i = 0; i < 4; i++) o[i] = (v[i] - mu) * rstd * g[i] + be[i];
    *(f32x4*)(out + (size_t)row * D_ + t * 4) = o;
}

// ---------------------------------------------------------------------------
extern "C" void kernel_launch(void* const* d_in, const int* in_sizes, int n_in,
                              void* d_out, int out_size, void* d_ws, size_t ws_size,
                              hipStream_t stream)
{
    const float* query = (const float*)d_in[0];
    const float* key   = (const float*)d_in[1];
    const float* value = (const float*)d_in[2];
    const int*   mask  = (const int*)d_in[3];
    const float* bias  = (const float*)d_in[4];
    const float* Wq    = (const float*)d_in[5];
    const float* bq    = (const float*)d_in[6];
    const float* Wk    = (const float*)d_in[7];
    const float* bk    = (const float*)d_in[8];
    const float* Wv    = (const float*)d_in[9];
    const float* bv    = (const float*)d_in[10];
    const float* Wo    = (const float*)d_in[11];
    const float* bo    = (const float*)d_in[12];
    const float* gamma = (const float*)d_in[13];
    const float* beta  = (const float*)d_in[14];
    float* out = (float*)d_out;

    char* ws = (char*)d_ws;
    const size_t MB = 1024 * 1024;
    // layout (104 MB):
    //   0..48   xb (bf16 query/key/value)  [dead after gemm_qkv]
    //   0..16   ctx (attn out)             [overlaps dead xb]
    //   16..48  tmp (gemm_out fp32)        [overlaps dead xb]
    //   48..56  wb (bf16 Wq,Wk,Wv,Wo)
    //   56..72  qb ; 72..88 kgt ; 88..104 vgt
    bf16_t* xb  = (bf16_t*)(ws);
    bf16_t* ctx = (bf16_t*)(ws);
    float*  tmp = (float*)(ws + 16 * MB);
    bf16_t* wb  = (bf16_t*)(ws + 48 * MB);
    bf16_t* qb  = (bf16_t*)(ws + 56 * MB);
    bf16_t* kgt = (bf16_t*)(ws + 72 * MB);
    bf16_t* vgt = (bf16_t*)(ws + 88 * MB);

    cvt_bf16<<<dim3(4096, 3), 256, 0, stream>>>(query, key, value, query, xb, 8192 * 1024);
    cvt_bf16<<<dim3(512, 4), 256, 0, stream>>>(Wq, Wk, Wv, Wo, wb, 1024 * 1024);
    gemm_qkv<<<dim3(64, 8, 3), 256, 0, stream>>>(xb, wb, bq, bk, bv, qb, kgt, vgt);
    attn_kernel<<<dim3(1024), 256, 0, stream>>>(qb, kgt, vgt, bias, mask, ctx);
    gemm_out<<<dim3(64, 8), 256, 0, stream>>>(ctx, wb + (size_t)3 * 1024 * 1024, bo, query, tmp);
    ln_kernel<<<dim3(8192), 256, 0, stream>>>(tmp, gamma, beta, out);
}

// Round 15
// 325.062 us; speedup vs baseline: 1.0472x; 1.0472x over previous
//
#include <hip/hip_runtime.h>
#include <hip/hip_bf16.h>

// ---------------------------------------------------------------------------
// Problem constants
#define B_   4
#define SQ_  2048
#define SK_  2048
#define D_   1024
#define H_   16
#define HD_  64

#define LOG2E 1.4426950408889634f

typedef __bf16 bf16_t;
typedef bf16_t bf16x8 __attribute__((ext_vector_type(8)));
typedef bf16_t bf16x4 __attribute__((ext_vector_type(4)));
typedef float  f32x4  __attribute__((ext_vector_type(4)));
typedef int    i32x4  __attribute__((ext_vector_type(4)));
typedef unsigned u32x2 __attribute__((ext_vector_type(2)));

// MFMA 16x16x32 bf16 verified layouts (learn_hip m89/m91):
//   A operand: lane l, elem j -> A[m = l&15][k = (l>>4)*8 + j]
//   B operand: lane l, elem j -> B[k = (l>>4)*8 + j][n = l&15]
//   C/D:       lane l, reg  r -> D[m = (l>>4)*4 + r][n = l&15]

// Tiled K layout (per (b,h,kt) 64x64 tile): elem(kp,d) at
//   kp*64 + ((d>>3) ^ (kp&7))*8 + (d&7)
// Tiled V layout: column-permuted to match P-frag k-perm:
//   col v -> chunk = ((v>>5)&1)*4 + ((v>>2)&3), j = ((v>>4)&1)*4 + (v&3)
//   elem(d,v) at d*64 + ((chunk ^ (d&7))*8) + j

__device__ __forceinline__ void gll16(const bf16_t* g, bf16_t* l) {
    __builtin_amdgcn_global_load_lds(
        (const __attribute__((address_space(1))) unsigned int*)g,
        (__attribute__((address_space(3))) unsigned int*)l, 16, 0, 0);
}
__device__ __forceinline__ void gll16f(const float* g, float* l) {
    __builtin_amdgcn_global_load_lds(
        (const __attribute__((address_space(1))) unsigned int*)g,
        (__attribute__((address_space(3))) unsigned int*)l, 16, 0, 0);
}

// ---------------------------------------------------------------------------
// fp32 -> bf16 convert prepass (weights only now). y selects source.
__global__ __launch_bounds__(256) void cvt_bf16(
    const float* __restrict__ p0, const float* __restrict__ p1,
    const float* __restrict__ p2, const float* __restrict__ p3,
    bf16_t* __restrict__ d, int n)
{
    int y = blockIdx.y;
    const float* s = (y == 0) ? p0 : (y == 1) ? p1 : (y == 2) ? p2 : p3;
    int i = (blockIdx.x * 256 + threadIdx.x) * 8;
    f32x4 a = *(const f32x4*)(s + i);
    f32x4 b = *(const f32x4*)(s + i + 4);
    bf16x8 o;
    #pragma unroll
    for (int j = 0; j < 4; j++) { o[j] = (bf16_t)a[j]; o[4 + j] = (bf16_t)b[j]; }
    *(bf16x8*)(d + (size_t)y * n + i) = o;
}

// ---------------------------------------------------------------------------
// QKV GEMM: A = X fp32 [8192][1024] staged DIRECTLY via global_load_lds into
// a fp32 LDS tile (no cvt prepass, no staging VALU); bf16 conversion happens
// at fragment read (2x ds_read_b128 + cvt_pk per frag). B = W bf16 (tiny
// prepass). A LDS chunks (16B) XOR-swizzled by row&7: frag-read lanes hit
// 2 rows/bank = free 2-way conflict (m136). 128x128 tile, BK=32, dbuf.
__global__ __launch_bounds__(256) void gemm_qkv(
    const float* __restrict__ xq, const float* __restrict__ xk, const float* __restrict__ xv,
    const bf16_t* __restrict__ wb,   // [4][1024][1024] (0..2 used)
    const float* __restrict__ bq, const float* __restrict__ bk, const float* __restrict__ bv,
    bf16_t* __restrict__ oq, bf16_t* __restrict__ ok, bf16_t* __restrict__ ov)
{
    __shared__ __align__(16) float  lAf[2][4096];   // 128 rows x 32 f32, 2x16KB
    __shared__ __align__(16) bf16_t lB[2][4096];    // 128 rows x 32 bf16, 2x8KB

    int z = blockIdx.z;
    const float* A = (z == 0) ? xq : (z == 1) ? xk : xv;
    const bf16_t* Bm = wb + (size_t)z * 1024 * 1024;
    const float* bias = (z == 0) ? bq : (z == 1) ? bk : bv;
    bf16_t* out = (z == 0) ? oq : (z == 1) ? ok : ov;

    int tid = threadIdx.x;
    int w = tid >> 6, l = tid & 63, lr = l & 15, lg = l >> 4;
    int m0 = blockIdx.x * 128, n0 = blockIdx.y * 128;
    int wm = (w >> 1) * 64, wn = (w & 1) * 64;

    f32x4 zero4 = {0.f, 0.f, 0.f, 0.f};
    f32x4 acc[4][4];
    #pragma unroll
    for (int i = 0; i < 4; i++)
        #pragma unroll
        for (int j = 0; j < 4; j++) acc[i][j] = zero4;

    // A staging: 1024 slots of 16B (row = s>>3, chunk c = s&7), 4 per thread.
    // Storage chunk c holds GLOBAL chunk (c ^ (row&7))  [involution].
    int as0 = tid, as1 = tid + 256, as2 = tid + 512, as3 = tid + 768;
    int ar0 = as0 >> 3, ar1 = as1 >> 3, ar2 = as2 >> 3, ar3 = as3 >> 3;
    const float* a_p0 = A + (size_t)(m0 + ar0) * 1024 + (((as0 & 7) ^ (ar0 & 7)) * 4);
    const float* a_p1 = A + (size_t)(m0 + ar1) * 1024 + (((as1 & 7) ^ (ar1 & 7)) * 4);
    const float* a_p2 = A + (size_t)(m0 + ar2) * 1024 + (((as2 & 7) ^ (ar2 & 7)) * 4);
    const float* a_p3 = A + (size_t)(m0 + ar3) * 1024 + (((as3 & 7) ^ (ar3 & 7)) * 4);

    // B staging: 512 slots of 16B (row = s>>2, chunk = s&3), 2 per thread.
    int bs0 = tid, bs1 = tid + 256;
    int br0 = bs0 >> 2, br1 = bs1 >> 2;
    const bf16_t* b_p0 = Bm + (size_t)(n0 + br0) * 1024 + (((bs0 & 3) ^ ((br0 >> 1) & 3)) * 8);
    const bf16_t* b_p1 = Bm + (size_t)(n0 + br1) * 1024 + (((bs1 & 3) ^ ((br1 >> 1) & 3)) * 8);

    auto stage = [&](int buf, int kt) {
        gll16f(a_p0 + kt * 32, &lAf[buf][as0 * 4]);
        gll16f(a_p1 + kt * 32, &lAf[buf][as1 * 4]);
        gll16f(a_p2 + kt * 32, &lAf[buf][as2 * 4]);
        gll16f(a_p3 + kt * 32, &lAf[buf][as3 * 4]);
        gll16(b_p0 + kt * 32, &lB[buf][bs0 * 8]);
        gll16(b_p1 + kt * 32, &lB[buf][bs1 * 8]);
    };

    stage(0, 0);
    int buf = 0;
    #pragma unroll 1
    for (int kt = 0; kt < 32; ++kt) {
        __syncthreads();                 // drains stage(kt)
        if (kt + 1 < 32) stage(buf ^ 1, kt + 1);
        bf16x8 af[4], bfr[4];
        #pragma unroll
        for (int i = 0; i < 4; i++) {
            int ra = wm + i * 16 + lr;
            int e = ra & 7;
            const float* arow = &lAf[buf][ra * 32];
            f32x4 lo = *(const f32x4*)(arow + ((( lg * 2)      ^ e) * 4));
            f32x4 hi = *(const f32x4*)(arow + ((((lg * 2) + 1) ^ e) * 4));
            bf16x8 a8;
            #pragma unroll
            for (int j = 0; j < 4; j++) { a8[j] = (bf16_t)lo[j]; a8[4 + j] = (bf16_t)hi[j]; }
            af[i] = a8;
            int rb = wn + i * 16 + lr;
            bfr[i] = *(const bf16x8*)&lB[buf][rb * 32 + ((lg ^ ((rb >> 1) & 3)) * 8)];
        }
        #pragma unroll
        for (int mi = 0; mi < 4; mi++)
            #pragma unroll
            for (int ni = 0; ni < 4; ni++)
                acc[mi][ni] = __builtin_amdgcn_mfma_f32_16x16x32_bf16(af[mi], bfr[ni], acc[mi][ni], 0, 0, 0);
        buf ^= 1;
    }

    #pragma unroll
    for (int mi = 0; mi < 4; mi++) {
        int row = m0 + wm + mi * 16 + lg * 4;       // row = b*2048 + s(or kpos)
        int bb_ = row >> 11;
        int s   = row & 2047;
        #pragma unroll
        for (int ni = 0; ni < 4; ni++) {
            int col = n0 + wn + ni * 16 + lr;       // col = h*64 + d
            int hh = col >> 6, d6 = col & 63;
            float bval = bias[col];
            if (z == 0) {
                // Q pre-scaled by 0.125*log2e so attn can use exp2 directly
                size_t obase = (((size_t)bb_ * H_ + hh) * SQ_ + s) * HD_ + d6;
                #pragma unroll
                for (int r = 0; r < 4; r++)
                    out[obase + (size_t)r * HD_] =
                        (bf16_t)((acc[mi][ni][r] + bval) * (0.125f * LOG2E));
            } else if (z == 1) {
                int kt = s >> 6, kpb = s & 63;
                size_t tb = (((size_t)bb_ * H_ + hh) * 32 + kt) * 4096;
                #pragma unroll
                for (int r = 0; r < 4; r++) {
                    int kp = kpb + r;
                    out[tb + (size_t)kp * 64 + (((d6 >> 3) ^ (kp & 7)) * 8) + (d6 & 7)] =
                        (bf16_t)(acc[mi][ni][r] + bval);
                }
            } else {
                int kt = s >> 6, kpb = s & 63;
                int chunk = ((kpb >> 5) & 1) * 4 + ((kpb >> 2) & 3);
                int jb    = ((kpb >> 4) & 1) * 4;
                size_t tb = (((size_t)bb_ * H_ + hh) * 32 + kt) * 4096;
                bf16x4 o4;
                #pragma unroll
                for (int r = 0; r < 4; r++) o4[r] = (bf16_t)(acc[mi][ni][r] + bval);
                *(bf16x4*)(out + tb + (size_t)d6 * 64 + ((chunk ^ (d6 & 7)) * 8) + jb) = o4;
            }
        }
    }
}

// ---------------------------------------------------------------------------
// O projection: tmp = ctx(bf16) @ Wo^T + bo + resid(fp32), fp32 out.
__global__ __launch_bounds__(256) void gemm_out(
    const bf16_t* __restrict__ A, const bf16_t* __restrict__ Bm,
    const float* __restrict__ bias, const float* __restrict__ resid,
    float* __restrict__ out)
{
    __shared__ __align__(16) bf16_t lA[2][4096];
    __shared__ __align__(16) bf16_t lB[2][4096];

    int tid = threadIdx.x;
    int w = tid >> 6, l = tid & 63, lr = l & 15, lg = l >> 4;
    int m0 = blockIdx.x * 128, n0 = blockIdx.y * 128;
    int wm = (w >> 1) * 64, wn = (w & 1) * 64;

    f32x4 zero4 = {0.f, 0.f, 0.f, 0.f};
    f32x4 acc[4][4];
    #pragma unroll
    for (int i = 0; i < 4; i++)
        #pragma unroll
        for (int j = 0; j < 4; j++) acc[i][j] = zero4;

    int s0 = tid, s1 = 256 + tid;
    int r0 = s0 >> 2, c0 = s0 & 3, r1 = s1 >> 2, c1 = s1 & 3;
    const bf16_t* a0 = A + (size_t)(m0 + r0) * 1024 + ((c0 ^ ((r0 >> 1) & 3)) * 8);
    const bf16_t* a1 = A + (size_t)(m0 + r1) * 1024 + ((c1 ^ ((r1 >> 1) & 3)) * 8);
    const bf16_t* b0 = Bm + (size_t)(n0 + r0) * 1024 + ((c0 ^ ((r0 >> 1) & 3)) * 8);
    const bf16_t* b1 = Bm + (size_t)(n0 + r1) * 1024 + ((c1 ^ ((r1 >> 1) & 3)) * 8);

    auto stage = [&](int buf, int kt) {
        gll16(a0 + kt * 32, &lA[buf][s0 * 8]);
        gll16(a1 + kt * 32, &lA[buf][s1 * 8]);
        gll16(b0 + kt * 32, &lB[buf][s0 * 8]);
        gll16(b1 + kt * 32, &lB[buf][s1 * 8]);
    };

    stage(0, 0);
    int buf = 0;
    #pragma unroll 1
    for (int kt = 0; kt < 32; ++kt) {
        __syncthreads();
        if (kt + 1 < 32) stage(buf ^ 1, kt + 1);
        bf16x8 af[4], bfr[4];
        #pragma unroll
        for (int i = 0; i < 4; i++) {
            int ra = wm + i * 16 + lr;
            af[i] = *(const bf16x8*)&lA[buf][ra * 32 + ((lg ^ ((ra >> 1) & 3)) * 8)];
            int rb = wn + i * 16 + lr;
            bfr[i] = *(const bf16x8*)&lB[buf][rb * 32 + ((lg ^ ((rb >> 1) & 3)) * 8)];
        }
        #pragma unroll
        for (int mi = 0; mi < 4; mi++)
            #pragma unroll
            for (int ni = 0; ni < 4; ni++)
                acc[mi][ni] = __builtin_amdgcn_mfma_f32_16x16x32_bf16(af[mi], bfr[ni], acc[mi][ni], 0, 0, 0);
        buf ^= 1;
    }

    #pragma unroll
    for (int mi = 0; mi < 4; mi++) {
        int row = m0 + wm + mi * 16 + lg * 4;
        #pragma unroll
        for (int ni = 0; ni < 4; ni++) {
            int col = n0 + wn + ni * 16 + lr;
            float bval = bias[col];
            #pragma unroll
            for (int r = 0; r < 4; r++) {
                size_t o = (size_t)(row + r) * D_ + col;
                out[o] = acc[mi][ni][r] + bval + resid[o];
            }
        }
    }
}

// ---------------------------------------------------------------------------
// Flash attention: (b,h,qt-of-128) per block, 4 waves x 32 q-rows (2 q-sets).
// r10 structure (single barrier/tile, stage-at-top) + ones-trick denominator
// + RAW v_exp_f32 via __builtin_amdgcn_exp2f (r14's exp2f was an OCML libcall
// with range fixup -> +9% VALUBusy; the builtin is the bare HW instruction,
// which correctly flushes the -43k masked inputs to 0).
__global__ __launch_bounds__(256) void attn_kernel(
    const bf16_t* __restrict__ qg, const bf16_t* __restrict__ kgt,
    const bf16_t* __restrict__ vgt, const float* __restrict__ bias,
    const int* __restrict__ mask, bf16_t* __restrict__ ctx)
{
    __shared__ __align__(16) bf16_t ksh[2][4096];
    __shared__ __align__(16) bf16_t vsh[2][4096];
    __shared__ __align__(8) unsigned char mlds[256];   // 2048 mask bits

    // Swizzle: the 4 batch-siblings of one (h,qt) share x mod 8 -> same XCD L2
    int x = blockIdx.x;              // 1024 blocks
    int g8 = x & 7;
    int rest = x >> 3;               // 0..127
    int b  = rest & 3;
    int tt = ((rest >> 2) << 3) | g8;   // 0..255
    int h  = tt >> 4;
    int qt = tt & 15;

    int tid = threadIdx.x;
    int w   = tid >> 6;
    int l   = tid & 63;
    int q16 = l & 15;
    int g   = l >> 4;
    int g4  = g * 4;

    int qrow0 = qt * 128 + w * 16 + q16;
    int qrow1 = qrow0 + 64;
    const bf16_t* qbase = qg + ((size_t)b * H_ + h) * SQ_ * HD_;
    bf16x8 qf00 = *(const bf16x8*)(qbase + (size_t)qrow0 * HD_ + g * 8);
    bf16x8 qf01 = *(const bf16x8*)(qbase + (size_t)qrow0 * HD_ + 32 + g * 8);
    bf16x8 qf10 = *(const bf16x8*)(qbase + (size_t)qrow1 * HD_ + g * 8);
    bf16x8 qf11 = *(const bf16x8*)(qbase + (size_t)qrow1 * HD_ + 32 + g * 8);

    const bf16_t* kt_base = kgt + ((size_t)b * H_ + h) * 32 * 4096;
    const bf16_t* vt_base = vgt + ((size_t)b * H_ + h) * 32 * 4096;
    const float* bias_row0 = bias + ((size_t)h * SQ_ + qrow0) * SK_;
    const float* bias_row1 = bias + ((size_t)h * SQ_ + qrow1) * SK_;

    f32x4 zero4 = {0.f, 0.f, 0.f, 0.f};
    f32x4 oacc0[4], oacc1[4];
    #pragma unroll
    for (int i = 0; i < 4; i++) { oacc0[i] = zero4; oacc1[i] = zero4; }
    f32x4 lacc0 = zero4, lacc1 = zero4;   // ones-trick denominator accumulators

    bf16x8 ones;
    #pragma unroll
    for (int i = 0; i < 8; i++) ones[i] = (bf16_t)1.0f;

    auto stage = [&](int buf, int t) {   // 4 gll16 per thread
        const bf16_t* ks = kt_base + (size_t)t * 4096 + tid * 8;
        const bf16_t* vs = vt_base + (size_t)t * 4096 + tid * 8;
        gll16(ks,        &ksh[buf][tid * 8]);
        gll16(ks + 2048, &ksh[buf][2048 + tid * 8]);
        gll16(vs,        &vsh[buf][tid * 8]);
        gll16(vs + 2048, &vsh[buf][2048 + tid * 8]);
    };

    // ---- prologue ----
    stage(0, 0);
    {
        const int* mp = mask + (size_t)b * SK_ + tid * 8;
        i32x4 u0 = *(const i32x4*)mp;
        i32x4 u1 = *(const i32x4*)(mp + 4);
        unsigned by = 0;
        #pragma unroll
        for (int j = 0; j < 4; j++) by |= (u0[j] != 0 ? 1u : 0u) << j;
        #pragma unroll
        for (int j = 0; j < 4; j++) by |= (u1[j] != 0 ? 1u : 0u) << (4 + j);
        mlds[tid] = (unsigned char)by;
    }
    __syncthreads();     // mlds visible; tile 0 staged

    #pragma unroll 1
    for (int t = 0; t < 32; ++t) {
        int buf = t & 1;
        // ---- stage next tile FIRST (full body of cover before the drain) ----
        if (t + 1 < 32) stage(buf ^ 1, t + 1);

        // ---- bias + mask issued early (latency hides under QK^T) ----
        f32x4 bb0[4], bb1[4];
        const float* bp0 = bias_row0 + t * 64 + g4;
        const float* bp1 = bias_row1 + t * 64 + g4;
        #pragma unroll
        for (int ni = 0; ni < 4; ni++) {
            bb0[ni] = *(const f32x4*)(bp0 + ni * 16);
            bb1[ni] = *(const f32x4*)(bp1 + ni * 16);
        }
        u32x2 mm = *(const u32x2*)&mlds[t * 8];
        unsigned lo = mm[0], hi = mm[1];

        // ---- S^T = K Q^T, both q-sets share K frags ----
        f32x4 s0[4], s1[4];
        __builtin_amdgcn_s_setprio(1);
        #pragma unroll
        for (int ni = 0; ni < 4; ni++) {
            int krow = ni * 16 + q16;
            const bf16_t* kr = &ksh[buf][0] + krow * 64;
            bf16x8 kf0 = *(const bf16x8*)(kr + ((g       ^ (krow & 7)) * 8));
            bf16x8 kf1 = *(const bf16x8*)(kr + (((4 + g) ^ (krow & 7)) * 8));
            s0[ni] = zero4; s1[ni] = zero4;
            s0[ni] = __builtin_amdgcn_mfma_f32_16x16x32_bf16(kf0, qf00, s0[ni], 0, 0, 0);
            s0[ni] = __builtin_amdgcn_mfma_f32_16x16x32_bf16(kf1, qf01, s0[ni], 0, 0, 0);
            s1[ni] = __builtin_amdgcn_mfma_f32_16x16x32_bf16(kf0, qf10, s1[ni], 0, 0, 0);
            s1[ni] = __builtin_amdgcn_mfma_f32_16x16x32_bf16(kf1, qf11, s1[ni], 0, 0, 0);
        }
        __builtin_amdgcn_s_setprio(0);

        unsigned n0_ = (lo >> g4) & 0xF;
        unsigned n1_ = (lo >> (16 + g4)) & 0xF;
        unsigned n2_ = (hi >> g4) & 0xF;
        unsigned n3_ = (hi >> (16 + g4)) & 0xF;

        bf16x8 pA0, pA1, pB0, pB1;
        #pragma unroll
        for (int r = 0; r < 4; r++) {
            float b00 = ((n0_ >> r) & 1) ? bb0[0][r] : -30000.f;
            float b01 = ((n1_ >> r) & 1) ? bb0[1][r] : -30000.f;
            float b02 = ((n2_ >> r) & 1) ? bb0[2][r] : -30000.f;
            float b03 = ((n3_ >> r) & 1) ? bb0[3][r] : -30000.f;
            pA0[r]     = (bf16_t)__builtin_amdgcn_exp2f(fmaf(b00, LOG2E, s0[0][r]));
            pA0[4 + r] = (bf16_t)__builtin_amdgcn_exp2f(fmaf(b01, LOG2E, s0[1][r]));
            pA1[r]     = (bf16_t)__builtin_amdgcn_exp2f(fmaf(b02, LOG2E, s0[2][r]));
            pA1[4 + r] = (bf16_t)__builtin_amdgcn_exp2f(fmaf(b03, LOG2E, s0[3][r]));
            float b10 = ((n0_ >> r) & 1) ? bb1[0][r] : -30000.f;
            float b11 = ((n1_ >> r) & 1) ? bb1[1][r] : -30000.f;
            float b12 = ((n2_ >> r) & 1) ? bb1[2][r] : -30000.f;
            float b13 = ((n3_ >> r) & 1) ? bb1[3][r] : -30000.f;
            pB0[r]     = (bf16_t)__builtin_amdgcn_exp2f(fmaf(b10, LOG2E, s1[0][r]));
            pB0[4 + r] = (bf16_t)__builtin_amdgcn_exp2f(fmaf(b11, LOG2E, s1[1][r]));
            pB1[r]     = (bf16_t)__builtin_amdgcn_exp2f(fmaf(b12, LOG2E, s1[2][r]));
            pB1[4 + r] = (bf16_t)__builtin_amdgcn_exp2f(fmaf(b13, LOG2E, s1[3][r]));
        }

        // ---- O^T += V^T P, denominators += ones^T P (colsum) ----
        __builtin_amdgcn_s_setprio(1);
        lacc0 = __builtin_amdgcn_mfma_f32_16x16x32_bf16(ones, pA0, lacc0, 0, 0, 0);
        lacc0 = __builtin_amdgcn_mfma_f32_16x16x32_bf16(ones, pA1, lacc0, 0, 0, 0);
        lacc1 = __builtin_amdgcn_mfma_f32_16x16x32_bf16(ones, pB0, lacc1, 0, 0, 0);
        lacc1 = __builtin_amdgcn_mfma_f32_16x16x32_bf16(ones, pB1, lacc1, 0, 0, 0);
        #pragma unroll
        for (int nd = 0; nd < 4; nd++) {
            int vrow = nd * 16 + q16;
            const bf16_t* vr = &vsh[buf][0] + vrow * 64;
            bf16x8 vf0 = *(const bf16x8*)(vr + ((g       ^ (vrow & 7)) * 8));
            bf16x8 vf1 = *(const bf16x8*)(vr + (((4 + g) ^ (vrow & 7)) * 8));
            oacc0[nd] = __builtin_amdgcn_mfma_f32_16x16x32_bf16(vf0, pA0, oacc0[nd], 0, 0, 0);
            oacc0[nd] = __builtin_amdgcn_mfma_f32_16x16x32_bf16(vf1, pA1, oacc0[nd], 0, 0, 0);
            oacc1[nd] = __builtin_amdgcn_mfma_f32_16x16x32_bf16(vf0, pB0, oacc1[nd], 0, 0, 0);
            oacc1[nd] = __builtin_amdgcn_mfma_f32_16x16x32_bf16(vf1, pB1, oacc1[nd], 0, 0, 0);
        }
        __builtin_amdgcn_s_setprio(0);

        // ---- single barrier per tile: drains stage(t+1), resolves WAR ----
        __syncthreads();
    }

    // ---- denominators: lacc[m][q16] = colsum P, identical across m ----
    float l_r0 = lacc0[0];
    float l_r1 = lacc1[0];
    float inv0 = (l_r0 > 0.f) ? 1.0f / l_r0 : 0.f;
    float inv1 = (l_r1 > 0.f) ? 1.0f / l_r1 : 0.f;

    bf16_t* cp0 = ctx + ((size_t)b * SQ_ + qrow0) * D_ + (size_t)h * HD_;
    bf16_t* cp1 = ctx + ((size_t)b * SQ_ + qrow1) * D_ + (size_t)h * HD_;
    #pragma unroll
    for (int nd = 0; nd < 4; nd++) {
        bf16x4 o4, o5;
        #pragma unroll
        for (int r = 0; r < 4; r++) {
            o4[r] = (bf16_t)(oacc0[nd][r] * inv0);
            o5[r] = (bf16_t)(oacc1[nd][r] * inv1);
        }
        *(bf16x4*)(cp0 + nd * 16 + g4) = o4;
        *(bf16x4*)(cp1 + nd * 16 + g4) = o5;
    }
}

// ---------------------------------------------------------------------------
// LayerNorm over D=1024, one block (256 threads) per row, fp32 in/out
__global__ __launch_bounds__(256) void ln_kernel(
    const float* __restrict__ x, const float* __restrict__ gamma,
    const float* __restrict__ beta, float* __restrict__ out)
{
    int row = blockIdx.x;
    int t = threadIdx.x;
    const float* src = x + (size_t)row * D_;
    f32x4 v = *(const f32x4*)(src + t * 4);
    float s  = v[0] + v[1] + v[2] + v[3];
    float s2 = v[0] * v[0] + v[1] * v[1] + v[2] * v[2] + v[3] * v[3];
    #pragma unroll
    for (int off = 32; off > 0; off >>= 1) {
        s  += __shfl_down(s, off);
        s2 += __shfl_down(s2, off);
    }
    __shared__ float red[8];
    int w = t >> 6, l = t & 63;
    if (l == 0) { red[w] = s; red[4 + w] = s2; }
    __syncthreads();
    if (t == 0) {
        red[0] = red[0] + red[1] + red[2] + red[3];
        red[4] = red[4] + red[5] + red[6] + red[7];
    }
    __syncthreads();
    float mu  = red[0] * (1.0f / D_);
    float var = red[4] * (1.0f / D_) - mu * mu;
    float rstd = rsqrtf(var + 1e-5f);
    f32x4 g  = *(const f32x4*)(gamma + t * 4);
    f32x4 be = *(const f32x4*)(beta + t * 4);
    f32x4 o;
    #pragma unroll
    for (int i = 0; i < 4; i++) o[i] = (v[i] - mu) * rstd * g[i] + be[i];
    *(f32x4*)(out + (size_t)row * D_ + t * 4) = o;
}

// ---------------------------------------------------------------------------
extern "C" void kernel_launch(void* const* d_in, const int* in_sizes, int n_in,
                              void* d_out, int out_size, void* d_ws, size_t ws_size,
                              hipStream_t stream)
{
    const float* query = (const float*)d_in[0];
    const float* key   = (const float*)d_in[1];
    const float* value = (const float*)d_in[2];
    const int*   mask  = (const int*)d_in[3];
    const float* bias  = (const float*)d_in[4];
    const float* Wq    = (const float*)d_in[5];
    const float* bq    = (const float*)d_in[6];
    const float* Wk    = (const float*)d_in[7];
    const float* bk    = (const float*)d_in[8];
    const float* Wv    = (const float*)d_in[9];
    const float* bv    = (const float*)d_in[10];
    const float* Wo    = (const float*)d_in[11];
    const float* bo    = (const float*)d_in[12];
    const float* gamma = (const float*)d_in[13];
    const float* beta  = (const float*)d_in[14];
    float* out = (float*)d_out;

    char* ws = (char*)d_ws;
    const size_t MB = 1024 * 1024;
    // layout (104 MB):
    //   0..16   ctx (attn out, bf16 [B,SQ,D])
    //   16..48  tmp (gemm_out fp32)
    //   48..56  wb (bf16 Wq,Wk,Wv,Wo)
    //   56..72  qb ; 72..88 kgt ; 88..104 vgt
    bf16_t* ctx = (bf16_t*)(ws);
    float*  tmp = (float*)(ws + 16 * MB);
    bf16_t* wb  = (bf16_t*)(ws + 48 * MB);
    bf16_t* qb  = (bf16_t*)(ws + 56 * MB);
    bf16_t* kgt = (bf16_t*)(ws + 72 * MB);
    bf16_t* vgt = (bf16_t*)(ws + 88 * MB);

    cvt_bf16<<<dim3(512, 4), 256, 0, stream>>>(Wq, Wk, Wv, Wo, wb, 1024 * 1024);
    gemm_qkv<<<dim3(64, 8, 3), 256, 0, stream>>>(query, key, value, wb,
                                                 bq, bk, bv, qb, kgt, vgt);
    attn_kernel<<<dim3(1024), 256, 0, stream>>>(qb, kgt, vgt, bias, mask, ctx);
    gemm_out<<<dim3(64, 8), 256, 0, stream>>>(ctx, wb + (size_t)3 * 1024 * 1024, bo, query, tmp);
    ln_kernel<<<dim3(8192), 256, 0, stream>>>(tmp, gamma, beta, out);
}

// Round 16
// 304.949 us; speedup vs baseline: 1.1163x; 1.0660x over previous
//
#include <hip/hip_runtime.h>
#include <hip/hip_bf16.h>

// ---------------------------------------------------------------------------
// Problem constants
#define B_   4
#define SQ_  2048
#define SK_  2048
#define D_   1024
#define H_   16
#define HD_  64

#define LOG2E 1.4426950408889634f

typedef __bf16 bf16_t;
typedef bf16_t bf16x8 __attribute__((ext_vector_type(8)));
typedef bf16_t bf16x4 __attribute__((ext_vector_type(4)));
typedef float  f32x4  __attribute__((ext_vector_type(4)));
typedef int    i32x4  __attribute__((ext_vector_type(4)));
typedef unsigned u32x2 __attribute__((ext_vector_type(2)));

// MFMA 16x16x32 bf16 verified layouts (learn_hip m89/m91):
//   A operand: lane l, elem j -> A[m = l&15][k = (l>>4)*8 + j]
//   B operand: lane l, elem j -> B[k = (l>>4)*8 + j][n = l&15]
//   C/D:       lane l, reg  r -> D[m = (l>>4)*4 + r][n = l&15]

// Tiled K layout (per (b,h,kt) 64x64 tile): elem(kp,d) at
//   kp*64 + ((d>>3) ^ (kp&7))*8 + (d&7)
// Tiled V layout: column-permuted to match P-frag k-perm:
//   col v -> chunk = ((v>>5)&1)*4 + ((v>>2)&3), j = ((v>>4)&1)*4 + (v&3)
//   elem(d,v) at d*64 + ((chunk ^ (d&7))*8) + j

__device__ __forceinline__ void gll16(const bf16_t* g, bf16_t* l) {
    __builtin_amdgcn_global_load_lds(
        (const __attribute__((address_space(1))) unsigned int*)g,
        (__attribute__((address_space(3))) unsigned int*)l, 16, 0, 0);
}
__device__ __forceinline__ void gll16f(const float* g, float* l) {
    __builtin_amdgcn_global_load_lds(
        (const __attribute__((address_space(1))) unsigned int*)g,
        (__attribute__((address_space(3))) unsigned int*)l, 16, 0, 0);
}

// ---------------------------------------------------------------------------
// fp32 -> bf16 convert prepass (weights only). y selects source.
__global__ __launch_bounds__(256) void cvt_bf16(
    const float* __restrict__ p0, const float* __restrict__ p1,
    const float* __restrict__ p2, const float* __restrict__ p3,
    bf16_t* __restrict__ d, int n)
{
    int y = blockIdx.y;
    const float* s = (y == 0) ? p0 : (y == 1) ? p1 : (y == 2) ? p2 : p3;
    int i = (blockIdx.x * 256 + threadIdx.x) * 8;
    f32x4 a = *(const f32x4*)(s + i);
    f32x4 b = *(const f32x4*)(s + i + 4);
    bf16x8 o;
    #pragma unroll
    for (int j = 0; j < 4; j++) { o[j] = (bf16_t)a[j]; o[4 + j] = (bf16_t)b[j]; }
    *(bf16x8*)(d + (size_t)y * n + i) = o;
}

// ---------------------------------------------------------------------------
// QKV GEMM: A = X fp32 staged directly via global_load_lds (fp32 LDS tile,
// XOR-swizzled 16B chunks, bf16 cvt at fragment read); B = W bf16 (prepass).
// 128x128 tile, BK=32, double-buffered, one __syncthreads per K-step.
__global__ __launch_bounds__(256) void gemm_qkv(
    const float* __restrict__ xq, const float* __restrict__ xk, const float* __restrict__ xv,
    const bf16_t* __restrict__ wb,   // [4][1024][1024] (0..2 used)
    const float* __restrict__ bq, const float* __restrict__ bk, const float* __restrict__ bv,
    bf16_t* __restrict__ oq, bf16_t* __restrict__ ok, bf16_t* __restrict__ ov)
{
    __shared__ __align__(16) float  lAf[2][4096];   // 128 rows x 32 f32
    __shared__ __align__(16) bf16_t lB[2][4096];    // 128 rows x 32 bf16

    int z = blockIdx.z;
    const float* A = (z == 0) ? xq : (z == 1) ? xk : xv;
    const bf16_t* Bm = wb + (size_t)z * 1024 * 1024;
    const float* bias = (z == 0) ? bq : (z == 1) ? bk : bv;
    bf16_t* out = (z == 0) ? oq : (z == 1) ? ok : ov;

    int tid = threadIdx.x;
    int w = tid >> 6, l = tid & 63, lr = l & 15, lg = l >> 4;
    int m0 = blockIdx.x * 128, n0 = blockIdx.y * 128;
    int wm = (w >> 1) * 64, wn = (w & 1) * 64;

    f32x4 zero4 = {0.f, 0.f, 0.f, 0.f};
    f32x4 acc[4][4];
    #pragma unroll
    for (int i = 0; i < 4; i++)
        #pragma unroll
        for (int j = 0; j < 4; j++) acc[i][j] = zero4;

    int as0 = tid, as1 = tid + 256, as2 = tid + 512, as3 = tid + 768;
    int ar0 = as0 >> 3, ar1 = as1 >> 3, ar2 = as2 >> 3, ar3 = as3 >> 3;
    const float* a_p0 = A + (size_t)(m0 + ar0) * 1024 + (((as0 & 7) ^ (ar0 & 7)) * 4);
    const float* a_p1 = A + (size_t)(m0 + ar1) * 1024 + (((as1 & 7) ^ (ar1 & 7)) * 4);
    const float* a_p2 = A + (size_t)(m0 + ar2) * 1024 + (((as2 & 7) ^ (ar2 & 7)) * 4);
    const float* a_p3 = A + (size_t)(m0 + ar3) * 1024 + (((as3 & 7) ^ (ar3 & 7)) * 4);

    int bs0 = tid, bs1 = tid + 256;
    int br0 = bs0 >> 2, br1 = bs1 >> 2;
    const bf16_t* b_p0 = Bm + (size_t)(n0 + br0) * 1024 + (((bs0 & 3) ^ ((br0 >> 1) & 3)) * 8);
    const bf16_t* b_p1 = Bm + (size_t)(n0 + br1) * 1024 + (((bs1 & 3) ^ ((br1 >> 1) & 3)) * 8);

    auto stage = [&](int buf, int kt) {
        gll16f(a_p0 + kt * 32, &lAf[buf][as0 * 4]);
        gll16f(a_p1 + kt * 32, &lAf[buf][as1 * 4]);
        gll16f(a_p2 + kt * 32, &lAf[buf][as2 * 4]);
        gll16f(a_p3 + kt * 32, &lAf[buf][as3 * 4]);
        gll16(b_p0 + kt * 32, &lB[buf][bs0 * 8]);
        gll16(b_p1 + kt * 32, &lB[buf][bs1 * 8]);
    };

    stage(0, 0);
    int buf = 0;
    #pragma unroll 1
    for (int kt = 0; kt < 32; ++kt) {
        __syncthreads();                 // drains stage(kt)
        if (kt + 1 < 32) stage(buf ^ 1, kt + 1);
        bf16x8 af[4], bfr[4];
        #pragma unroll
        for (int i = 0; i < 4; i++) {
            int ra = wm + i * 16 + lr;
            int e = ra & 7;
            const float* arow = &lAf[buf][ra * 32];
            f32x4 lo = *(const f32x4*)(arow + ((( lg * 2)      ^ e) * 4));
            f32x4 hi = *(const f32x4*)(arow + ((((lg * 2) + 1) ^ e) * 4));
            bf16x8 a8;
            #pragma unroll
            for (int j = 0; j < 4; j++) { a8[j] = (bf16_t)lo[j]; a8[4 + j] = (bf16_t)hi[j]; }
            af[i] = a8;
            int rb = wn + i * 16 + lr;
            bfr[i] = *(const bf16x8*)&lB[buf][rb * 32 + ((lg ^ ((rb >> 1) & 3)) * 8)];
        }
        #pragma unroll
        for (int mi = 0; mi < 4; mi++)
            #pragma unroll
            for (int ni = 0; ni < 4; ni++)
                acc[mi][ni] = __builtin_amdgcn_mfma_f32_16x16x32_bf16(af[mi], bfr[ni], acc[mi][ni], 0, 0, 0);
        buf ^= 1;
    }

    #pragma unroll
    for (int mi = 0; mi < 4; mi++) {
        int row = m0 + wm + mi * 16 + lg * 4;       // row = b*2048 + s(or kpos)
        int bb_ = row >> 11;
        int s   = row & 2047;
        #pragma unroll
        for (int ni = 0; ni < 4; ni++) {
            int col = n0 + wn + ni * 16 + lr;       // col = h*64 + d
            int hh = col >> 6, d6 = col & 63;
            float bval = bias[col];
            if (z == 0) {
                // Q pre-scaled by 0.125*log2e so attn can use exp2 directly
                size_t obase = (((size_t)bb_ * H_ + hh) * SQ_ + s) * HD_ + d6;
                #pragma unroll
                for (int r = 0; r < 4; r++)
                    out[obase + (size_t)r * HD_] =
                        (bf16_t)((acc[mi][ni][r] + bval) * (0.125f * LOG2E));
            } else if (z == 1) {
                int kt = s >> 6, kpb = s & 63;
                size_t tb = (((size_t)bb_ * H_ + hh) * 32 + kt) * 4096;
                #pragma unroll
                for (int r = 0; r < 4; r++) {
                    int kp = kpb + r;
                    out[tb + (size_t)kp * 64 + (((d6 >> 3) ^ (kp & 7)) * 8) + (d6 & 7)] =
                        (bf16_t)(acc[mi][ni][r] + bval);
                }
            } else {
                int kt = s >> 6, kpb = s & 63;
                int chunk = ((kpb >> 5) & 1) * 4 + ((kpb >> 2) & 3);
                int jb    = ((kpb >> 4) & 1) * 4;
                size_t tb = (((size_t)bb_ * H_ + hh) * 32 + kt) * 4096;
                bf16x4 o4;
                #pragma unroll
                for (int r = 0; r < 4; r++) o4[r] = (bf16_t)(acc[mi][ni][r] + bval);
                *(bf16x4*)(out + tb + (size_t)d6 * 64 + ((chunk ^ (d6 & 7)) * 8) + jb) = o4;
            }
        }
    }
}

// ---------------------------------------------------------------------------
// O projection: tmp(bf16) = ctx(bf16) @ Wo^T + bo + resid(fp32).
__global__ __launch_bounds__(256) void gemm_out(
    const bf16_t* __restrict__ A, const bf16_t* __restrict__ Bm,
    const float* __restrict__ bias, const float* __restrict__ resid,
    bf16_t* __restrict__ out)
{
    __shared__ __align__(16) bf16_t lA[2][4096];
    __shared__ __align__(16) bf16_t lB[2][4096];

    int tid = threadIdx.x;
    int w = tid >> 6, l = tid & 63, lr = l & 15, lg = l >> 4;
    int m0 = blockIdx.x * 128, n0 = blockIdx.y * 128;
    int wm = (w >> 1) * 64, wn = (w & 1) * 64;

    f32x4 zero4 = {0.f, 0.f, 0.f, 0.f};
    f32x4 acc[4][4];
    #pragma unroll
    for (int i = 0; i < 4; i++)
        #pragma unroll
        for (int j = 0; j < 4; j++) acc[i][j] = zero4;

    int s0 = tid, s1 = 256 + tid;
    int r0 = s0 >> 2, c0 = s0 & 3, r1 = s1 >> 2, c1 = s1 & 3;
    const bf16_t* a0 = A + (size_t)(m0 + r0) * 1024 + ((c0 ^ ((r0 >> 1) & 3)) * 8);
    const bf16_t* a1 = A + (size_t)(m0 + r1) * 1024 + ((c1 ^ ((r1 >> 1) & 3)) * 8);
    const bf16_t* b0 = Bm + (size_t)(n0 + r0) * 1024 + ((c0 ^ ((r0 >> 1) & 3)) * 8);
    const bf16_t* b1 = Bm + (size_t)(n0 + r1) * 1024 + ((c1 ^ ((r1 >> 1) & 3)) * 8);

    auto stage = [&](int buf, int kt) {
        gll16(a0 + kt * 32, &lA[buf][s0 * 8]);
        gll16(a1 + kt * 32, &lA[buf][s1 * 8]);
        gll16(b0 + kt * 32, &lB[buf][s0 * 8]);
        gll16(b1 + kt * 32, &lB[buf][s1 * 8]);
    };

    stage(0, 0);
    int buf = 0;
    #pragma unroll 1
    for (int kt = 0; kt < 32; ++kt) {
        __syncthreads();
        if (kt + 1 < 32) stage(buf ^ 1, kt + 1);
        bf16x8 af[4], bfr[4];
        #pragma unroll
        for (int i = 0; i < 4; i++) {
            int ra = wm + i * 16 + lr;
            af[i] = *(const bf16x8*)&lA[buf][ra * 32 + ((lg ^ ((ra >> 1) & 3)) * 8)];
            int rb = wn + i * 16 + lr;
            bfr[i] = *(const bf16x8*)&lB[buf][rb * 32 + ((lg ^ ((rb >> 1) & 3)) * 8)];
        }
        #pragma unroll
        for (int mi = 0; mi < 4; mi++)
            #pragma unroll
            for (int ni = 0; ni < 4; ni++)
                acc[mi][ni] = __builtin_amdgcn_mfma_f32_16x16x32_bf16(af[mi], bfr[ni], acc[mi][ni], 0, 0, 0);
        buf ^= 1;
    }

    #pragma unroll
    for (int mi = 0; mi < 4; mi++) {
        int row = m0 + wm + mi * 16 + lg * 4;
        #pragma unroll
        for (int ni = 0; ni < 4; ni++) {
            int col = n0 + wn + ni * 16 + lr;
            float bval = bias[col];
            #pragma unroll
            for (int r = 0; r < 4; r++) {
                size_t o = (size_t)(row + r) * D_ + col;
                out[o] = (bf16_t)(acc[mi][ni][r] + bval + resid[o]);
            }
        }
    }
}

// ---------------------------------------------------------------------------
// Flash attention: (b,h,qt-of-128) per block, 4 waves x 32 q-rows (2 q-sets).
// KBLK=128: stage a PAIR of 64-k tiles per LDS buffer (64 KB total) -> 16
// barrier rendezvous instead of 32 (per-step fixed cost amortized over 2x
// work; residency was LDS-independent at ~2 blocks/CU so the bigger tile is
// free). Body identical to r15: ones-trick denominator, raw v_exp_f32.
__global__ __launch_bounds__(256) void attn_kernel(
    const bf16_t* __restrict__ qg, const bf16_t* __restrict__ kgt,
    const bf16_t* __restrict__ vgt, const float* __restrict__ bias,
    const int* __restrict__ mask, bf16_t* __restrict__ ctx)
{
    __shared__ __align__(16) bf16_t ksh[2][8192];   // pair of 64x64 tiles
    __shared__ __align__(16) bf16_t vsh[2][8192];
    __shared__ __align__(8) unsigned char mlds[256];   // 2048 mask bits

    // Swizzle: the 4 batch-siblings of one (h,qt) share x mod 8 -> same XCD L2
    int x = blockIdx.x;              // 1024 blocks
    int g8 = x & 7;
    int rest = x >> 3;               // 0..127
    int b  = rest & 3;
    int tt = ((rest >> 2) << 3) | g8;   // 0..255
    int h  = tt >> 4;
    int qt = tt & 15;

    int tid = threadIdx.x;
    int w   = tid >> 6;
    int l   = tid & 63;
    int q16 = l & 15;
    int g   = l >> 4;
    int g4  = g * 4;

    int qrow0 = qt * 128 + w * 16 + q16;
    int qrow1 = qrow0 + 64;
    const bf16_t* qbase = qg + ((size_t)b * H_ + h) * SQ_ * HD_;
    bf16x8 qf00 = *(const bf16x8*)(qbase + (size_t)qrow0 * HD_ + g * 8);
    bf16x8 qf01 = *(const bf16x8*)(qbase + (size_t)qrow0 * HD_ + 32 + g * 8);
    bf16x8 qf10 = *(const bf16x8*)(qbase + (size_t)qrow1 * HD_ + g * 8);
    bf16x8 qf11 = *(const bf16x8*)(qbase + (size_t)qrow1 * HD_ + 32 + g * 8);

    const bf16_t* kt_base = kgt + ((size_t)b * H_ + h) * 32 * 4096;
    const bf16_t* vt_base = vgt + ((size_t)b * H_ + h) * 32 * 4096;
    const float* bias_row0 = bias + ((size_t)h * SQ_ + qrow0) * SK_;
    const float* bias_row1 = bias + ((size_t)h * SQ_ + qrow1) * SK_;

    f32x4 zero4 = {0.f, 0.f, 0.f, 0.f};
    f32x4 oacc0[4], oacc1[4];
    #pragma unroll
    for (int i = 0; i < 4; i++) { oacc0[i] = zero4; oacc1[i] = zero4; }
    f32x4 lacc0 = zero4, lacc1 = zero4;   // ones-trick denominator accumulators

    bf16x8 ones;
    #pragma unroll
    for (int i = 0; i < 8; i++) ones[i] = (bf16_t)1.0f;

    // stage a PAIR of tiles (16 KB K + 16 KB V): 8 gll16 per thread
    auto stagePair = [&](int buf, int pt) {
        const bf16_t* ks = kt_base + (size_t)pt * 8192 + tid * 8;
        const bf16_t* vs = vt_base + (size_t)pt * 8192 + tid * 8;
        #pragma unroll
        for (int c = 0; c < 4; c++) {
            gll16(ks + c * 2048, &ksh[buf][c * 2048 + tid * 8]);
            gll16(vs + c * 2048, &vsh[buf][c * 2048 + tid * 8]);
        }
    };

    auto body = [&](const bf16_t* kb, const bf16_t* vb, int t) {
        // ---- bias + mask issued early (latency hides under QK^T) ----
        f32x4 bb0[4], bb1[4];
        const float* bp0 = bias_row0 + t * 64 + g4;
        const float* bp1 = bias_row1 + t * 64 + g4;
        #pragma unroll
        for (int ni = 0; ni < 4; ni++) {
            bb0[ni] = *(const f32x4*)(bp0 + ni * 16);
            bb1[ni] = *(const f32x4*)(bp1 + ni * 16);
        }
        u32x2 mm = *(const u32x2*)&mlds[t * 8];
        unsigned lo = mm[0], hi = mm[1];

        // ---- S^T = K Q^T, both q-sets share K frags ----
        f32x4 s0[4], s1[4];
        __builtin_amdgcn_s_setprio(1);
        #pragma unroll
        for (int ni = 0; ni < 4; ni++) {
            int krow = ni * 16 + q16;
            const bf16_t* kr = kb + krow * 64;
            bf16x8 kf0 = *(const bf16x8*)(kr + ((g       ^ (krow & 7)) * 8));
            bf16x8 kf1 = *(const bf16x8*)(kr + (((4 + g) ^ (krow & 7)) * 8));
            s0[ni] = zero4; s1[ni] = zero4;
            s0[ni] = __builtin_amdgcn_mfma_f32_16x16x32_bf16(kf0, qf00, s0[ni], 0, 0, 0);
            s0[ni] = __builtin_amdgcn_mfma_f32_16x16x32_bf16(kf1, qf01, s0[ni], 0, 0, 0);
            s1[ni] = __builtin_amdgcn_mfma_f32_16x16x32_bf16(kf0, qf10, s1[ni], 0, 0, 0);
            s1[ni] = __builtin_amdgcn_mfma_f32_16x16x32_bf16(kf1, qf11, s1[ni], 0, 0, 0);
        }
        __builtin_amdgcn_s_setprio(0);

        unsigned n0_ = (lo >> g4) & 0xF;
        unsigned n1_ = (lo >> (16 + g4)) & 0xF;
        unsigned n2_ = (hi >> g4) & 0xF;
        unsigned n3_ = (hi >> (16 + g4)) & 0xF;

        bf16x8 pA0, pA1, pB0, pB1;
        #pragma unroll
        for (int r = 0; r < 4; r++) {
            float b00 = ((n0_ >> r) & 1) ? bb0[0][r] : -30000.f;
            float b01 = ((n1_ >> r) & 1) ? bb0[1][r] : -30000.f;
            float b02 = ((n2_ >> r) & 1) ? bb0[2][r] : -30000.f;
            float b03 = ((n3_ >> r) & 1) ? bb0[3][r] : -30000.f;
            pA0[r]     = (bf16_t)__builtin_amdgcn_exp2f(fmaf(b00, LOG2E, s0[0][r]));
            pA0[4 + r] = (bf16_t)__builtin_amdgcn_exp2f(fmaf(b01, LOG2E, s0[1][r]));
            pA1[r]     = (bf16_t)__builtin_amdgcn_exp2f(fmaf(b02, LOG2E, s0[2][r]));
            pA1[4 + r] = (bf16_t)__builtin_amdgcn_exp2f(fmaf(b03, LOG2E, s0[3][r]));
            float b10 = ((n0_ >> r) & 1) ? bb1[0][r] : -30000.f;
            float b11 = ((n1_ >> r) & 1) ? bb1[1][r] : -30000.f;
            float b12 = ((n2_ >> r) & 1) ? bb1[2][r] : -30000.f;
            float b13 = ((n3_ >> r) & 1) ? bb1[3][r] : -30000.f;
            pB0[r]     = (bf16_t)__builtin_amdgcn_exp2f(fmaf(b10, LOG2E, s1[0][r]));
            pB0[4 + r] = (bf16_t)__builtin_amdgcn_exp2f(fmaf(b11, LOG2E, s1[1][r]));
            pB1[r]     = (bf16_t)__builtin_amdgcn_exp2f(fmaf(b12, LOG2E, s1[2][r]));
            pB1[4 + r] = (bf16_t)__builtin_amdgcn_exp2f(fmaf(b13, LOG2E, s1[3][r]));
        }

        // ---- O^T += V^T P, denominators += ones^T P (colsum) ----
        __builtin_amdgcn_s_setprio(1);
        lacc0 = __builtin_amdgcn_mfma_f32_16x16x32_bf16(ones, pA0, lacc0, 0, 0, 0);
        lacc0 = __builtin_amdgcn_mfma_f32_16x16x32_bf16(ones, pA1, lacc0, 0, 0, 0);
        lacc1 = __builtin_amdgcn_mfma_f32_16x16x32_bf16(ones, pB0, lacc1, 0, 0, 0);
        lacc1 = __builtin_amdgcn_mfma_f32_16x16x32_bf16(ones, pB1, lacc1, 0, 0, 0);
        #pragma unroll
        for (int nd = 0; nd < 4; nd++) {
            int vrow = nd * 16 + q16;
            const bf16_t* vr = vb + vrow * 64;
            bf16x8 vf0 = *(const bf16x8*)(vr + ((g       ^ (vrow & 7)) * 8));
            bf16x8 vf1 = *(const bf16x8*)(vr + (((4 + g) ^ (vrow & 7)) * 8));
            oacc0[nd] = __builtin_amdgcn_mfma_f32_16x16x32_bf16(vf0, pA0, oacc0[nd], 0, 0, 0);
            oacc0[nd] = __builtin_amdgcn_mfma_f32_16x16x32_bf16(vf1, pA1, oacc0[nd], 0, 0, 0);
            oacc1[nd] = __builtin_amdgcn_mfma_f32_16x16x32_bf16(vf0, pB0, oacc1[nd], 0, 0, 0);
            oacc1[nd] = __builtin_amdgcn_mfma_f32_16x16x32_bf16(vf1, pB1, oacc1[nd], 0, 0, 0);
        }
        __builtin_amdgcn_s_setprio(0);
    };

    // ---- prologue ----
    stagePair(0, 0);
    {
        const int* mp = mask + (size_t)b * SK_ + tid * 8;
        i32x4 u0 = *(const i32x4*)mp;
        i32x4 u1 = *(const i32x4*)(mp + 4);
        unsigned by = 0;
        #pragma unroll
        for (int j = 0; j < 4; j++) by |= (u0[j] != 0 ? 1u : 0u) << j;
        #pragma unroll
        for (int j = 0; j < 4; j++) by |= (u1[j] != 0 ? 1u : 0u) << (4 + j);
        mlds[tid] = (unsigned char)by;
    }
    __syncthreads();     // mlds visible; pair 0 staged

    #pragma unroll 1
    for (int pt = 0; pt < 16; ++pt) {
        int buf = pt & 1;
        // stage next pair FIRST: two bodies of cover before the barrier drain
        if (pt + 1 < 16) stagePair(buf ^ 1, pt + 1);
        body(&ksh[buf][0],    &vsh[buf][0],    2 * pt);
        body(&ksh[buf][4096], &vsh[buf][4096], 2 * pt + 1);
        // single barrier per PAIR: drains stagePair(pt+1), resolves WAR
        __syncthreads();
    }

    // ---- denominators: lacc[m][q16] = colsum P, identical across m ----
    float l_r0 = lacc0[0];
    float l_r1 = lacc1[0];
    float inv0 = (l_r0 > 0.f) ? 1.0f / l_r0 : 0.f;
    float inv1 = (l_r1 > 0.f) ? 1.0f / l_r1 : 0.f;

    bf16_t* cp0 = ctx + ((size_t)b * SQ_ + qrow0) * D_ + (size_t)h * HD_;
    bf16_t* cp1 = ctx + ((size_t)b * SQ_ + qrow1) * D_ + (size_t)h * HD_;
    #pragma unroll
    for (int nd = 0; nd < 4; nd++) {
        bf16x4 o4, o5;
        #pragma unroll
        for (int r = 0; r < 4; r++) {
            o4[r] = (bf16_t)(oacc0[nd][r] * inv0);
            o5[r] = (bf16_t)(oacc1[nd][r] * inv1);
        }
        *(bf16x4*)(cp0 + nd * 16 + g4) = o4;
        *(bf16x4*)(cp1 + nd * 16 + g4) = o5;
    }
}

// ---------------------------------------------------------------------------
// LayerNorm over D=1024, one block (256 threads) per row; x in bf16, out fp32
__global__ __launch_bounds__(256) void ln_kernel(
    const bf16_t* __restrict__ x, const float* __restrict__ gamma,
    const float* __restrict__ beta, float* __restrict__ out)
{
    int row = blockIdx.x;
    int t = threadIdx.x;
    const bf16_t* src = x + (size_t)row * D_;
    bf16x4 v4 = *(const bf16x4*)(src + t * 4);
    f32x4 v;
    #pragma unroll
    for (int i = 0; i < 4; i++) v[i] = (float)v4[i];
    float s  = v[0] + v[1] + v[2] + v[3];
    float s2 = v[0] * v[0] + v[1] * v[1] + v[2] * v[2] + v[3] * v[3];
    #pragma unroll
    for (int off = 32; off > 0; off >>= 1) {
        s  += __shfl_down(s, off);
        s2 += __shfl_down(s2, off);
    }
    __shared__ float red[8];
    int w = t >> 6, l = t & 63;
    if (l == 0) { red[w] = s; red[4 + w] = s2; }
    __syncthreads();
    if (t == 0) {
        red[0] = red[0] + red[1] + red[2] + red[3];
        red[4] = red[4] + red[5] + red[6] + red[7];
    }
    __syncthreads();
    float mu  = red[0] * (1.0f / D_);
    float var = red[4] * (1.0f / D_) - mu * mu;
    float rstd = rsqrtf(var + 1e-5f);
    f32x4 g  = *(const f32x4*)(gamma + t * 4);
    f32x4 be = *(const f32x4*)(beta + t * 4);
    f32x4 o;
    #pragma unroll
    for (int i = 0; i < 4; i++) o[i] = (v[i] - mu) * rstd * g[i] + be[i];
    *(f32x4*)(out + (size_t)row * D_ + t * 4) = o;
}

// ---------------------------------------------------------------------------
extern "C" void kernel_launch(void* const* d_in, const int* in_sizes, int n_in,
                              void* d_out, int out_size, void* d_ws, size_t ws_size,
                              hipStream_t stream)
{
    const float* query = (const float*)d_in[0];
    const float* key   = (const float*)d_in[1];
    const float* value = (const float*)d_in[2];
    const int*   mask  = (const int*)d_in[3];
    const float* bias  = (const float*)d_in[4];
    const float* Wq    = (const float*)d_in[5];
    const float* bq    = (const float*)d_in[6];
    const float* Wk    = (const float*)d_in[7];
    const float* bk    = (const float*)d_in[8];
    const float* Wv    = (const float*)d_in[9];
    const float* bv    = (const float*)d_in[10];
    const float* Wo    = (const float*)d_in[11];
    const float* bo    = (const float*)d_in[12];
    const float* gamma = (const float*)d_in[13];
    const float* beta  = (const float*)d_in[14];
    float* out = (float*)d_out;

    char* ws = (char*)d_ws;
    const size_t MB = 1024 * 1024;
    // layout (104 MB):
    //   0..16   ctx (attn out, bf16 [B,SQ,D])
    //   16..32  tmp (gemm_out bf16 x = ctx@Wo+bo+resid)
    //   48..56  wb (bf16 Wq,Wk,Wv,Wo)
    //   56..72  qb ; 72..88 kgt ; 88..104 vgt
    bf16_t* ctx = (bf16_t*)(ws);
    bf16_t* tmp = (bf16_t*)(ws + 16 * MB);
    bf16_t* wb  = (bf16_t*)(ws + 48 * MB);
    bf16_t* qb  = (bf16_t*)(ws + 56 * MB);
    bf16_t* kgt = (bf16_t*)(ws + 72 * MB);
    bf16_t* vgt = (bf16_t*)(ws + 88 * MB);

    cvt_bf16<<<dim3(512, 4), 256, 0, stream>>>(Wq, Wk, Wv, Wo, wb, 1024 * 1024);
    gemm_qkv<<<dim3(64, 8, 3), 256, 0, stream>>>(query, key, value, wb,
                                                 bq, bk, bv, qb, kgt, vgt);
    attn_kernel<<<dim3(1024), 256, 0, stream>>>(qb, kgt, vgt, bias, mask, ctx);
    gemm_out<<<dim3(64, 8), 256, 0, stream>>>(ctx, wb + (size_t)3 * 1024 * 1024, bo, query, tmp);
    ln_kernel<<<dim3(8192), 256, 0, stream>>>(tmp, gamma, beta, out);
}

// Round 17
// 302.884 us; speedup vs baseline: 1.1239x; 1.0068x over previous
//
#include <hip/hip_runtime.h>
#include <hip/hip_bf16.h>

// ---------------------------------------------------------------------------
// Problem constants
#define B_   4
#define SQ_  2048
#define SK_  2048
#define D_   1024
#define H_   16
#define HD_  64

#define LOG2E 1.4426950408889634f

typedef __bf16 bf16_t;
typedef bf16_t bf16x8 __attribute__((ext_vector_type(8)));
typedef bf16_t bf16x4 __attribute__((ext_vector_type(4)));
typedef float  f32x4  __attribute__((ext_vector_type(4)));
typedef int    i32x4  __attribute__((ext_vector_type(4)));
typedef unsigned u32x2 __attribute__((ext_vector_type(2)));

// MFMA 16x16x32 bf16 verified layouts (learn_hip m89/m91):
//   A operand: lane l, elem j -> A[m = l&15][k = (l>>4)*8 + j]
//   B operand: lane l, elem j -> B[k = (l>>4)*8 + j][n = l&15]
//   C/D:       lane l, reg  r -> D[m = (l>>4)*4 + r][n = l&15]

// Tiled K layout (per (b,h,kt) 64x64 tile): elem(kp,d) at
//   kp*64 + ((d>>3) ^ (kp&7))*8 + (d&7)
// Tiled V layout: column-permuted to match P-frag k-perm:
//   col v -> chunk = ((v>>5)&1)*4 + ((v>>2)&3), j = ((v>>4)&1)*4 + (v&3)
//   elem(d,v) at d*64 + ((chunk ^ (d&7))*8) + j

__device__ __forceinline__ void gll16(const bf16_t* g, bf16_t* l) {
    __builtin_amdgcn_global_load_lds(
        (const __attribute__((address_space(1))) unsigned int*)g,
        (__attribute__((address_space(3))) unsigned int*)l, 16, 0, 0);
}
__device__ __forceinline__ void gll16f(const float* g, float* l) {
    __builtin_amdgcn_global_load_lds(
        (const __attribute__((address_space(1))) unsigned int*)g,
        (__attribute__((address_space(3))) unsigned int*)l, 16, 0, 0);
}

// ---------------------------------------------------------------------------
// fp32 -> bf16 convert prepass (weights only). y selects source.
__global__ __launch_bounds__(256) void cvt_bf16(
    const float* __restrict__ p0, const float* __restrict__ p1,
    const float* __restrict__ p2, const float* __restrict__ p3,
    bf16_t* __restrict__ d, int n)
{
    int y = blockIdx.y;
    const float* s = (y == 0) ? p0 : (y == 1) ? p1 : (y == 2) ? p2 : p3;
    int i = (blockIdx.x * 256 + threadIdx.x) * 8;
    f32x4 a = *(const f32x4*)(s + i);
    f32x4 b = *(const f32x4*)(s + i + 4);
    bf16x8 o;
    #pragma unroll
    for (int j = 0; j < 4; j++) { o[j] = (bf16_t)a[j]; o[4 + j] = (bf16_t)b[j]; }
    *(bf16x8*)(d + (size_t)y * n + i) = o;
}

// ---------------------------------------------------------------------------
// QKV GEMM: A = X fp32 staged directly via global_load_lds (fp32 LDS tile,
// XOR-swizzled 16B chunks, bf16 cvt at fragment read); B = W bf16 (prepass).
// 128x128 tile, BK=32, double-buffered, one __syncthreads per K-step.
__global__ __launch_bounds__(256) void gemm_qkv(
    const float* __restrict__ xq, const float* __restrict__ xk, const float* __restrict__ xv,
    const bf16_t* __restrict__ wb,   // [4][1024][1024] (0..2 used)
    const float* __restrict__ bq, const float* __restrict__ bk, const float* __restrict__ bv,
    bf16_t* __restrict__ oq, bf16_t* __restrict__ ok, bf16_t* __restrict__ ov)
{
    __shared__ __align__(16) float  lAf[2][4096];   // 128 rows x 32 f32
    __shared__ __align__(16) bf16_t lB[2][4096];    // 128 rows x 32 bf16

    int z = blockIdx.z;
    const float* A = (z == 0) ? xq : (z == 1) ? xk : xv;
    const bf16_t* Bm = wb + (size_t)z * 1024 * 1024;
    const float* bias = (z == 0) ? bq : (z == 1) ? bk : bv;
    bf16_t* out = (z == 0) ? oq : (z == 1) ? ok : ov;

    int tid = threadIdx.x;
    int w = tid >> 6, l = tid & 63, lr = l & 15, lg = l >> 4;
    int m0 = blockIdx.x * 128, n0 = blockIdx.y * 128;
    int wm = (w >> 1) * 64, wn = (w & 1) * 64;

    f32x4 zero4 = {0.f, 0.f, 0.f, 0.f};
    f32x4 acc[4][4];
    #pragma unroll
    for (int i = 0; i < 4; i++)
        #pragma unroll
        for (int j = 0; j < 4; j++) acc[i][j] = zero4;

    int as0 = tid, as1 = tid + 256, as2 = tid + 512, as3 = tid + 768;
    int ar0 = as0 >> 3, ar1 = as1 >> 3, ar2 = as2 >> 3, ar3 = as3 >> 3;
    const float* a_p0 = A + (size_t)(m0 + ar0) * 1024 + (((as0 & 7) ^ (ar0 & 7)) * 4);
    const float* a_p1 = A + (size_t)(m0 + ar1) * 1024 + (((as1 & 7) ^ (ar1 & 7)) * 4);
    const float* a_p2 = A + (size_t)(m0 + ar2) * 1024 + (((as2 & 7) ^ (ar2 & 7)) * 4);
    const float* a_p3 = A + (size_t)(m0 + ar3) * 1024 + (((as3 & 7) ^ (ar3 & 7)) * 4);

    int bs0 = tid, bs1 = tid + 256;
    int br0 = bs0 >> 2, br1 = bs1 >> 2;
    const bf16_t* b_p0 = Bm + (size_t)(n0 + br0) * 1024 + (((bs0 & 3) ^ ((br0 >> 1) & 3)) * 8);
    const bf16_t* b_p1 = Bm + (size_t)(n0 + br1) * 1024 + (((bs1 & 3) ^ ((br1 >> 1) & 3)) * 8);

    auto stage = [&](int buf, int kt) {
        gll16f(a_p0 + kt * 32, &lAf[buf][as0 * 4]);
        gll16f(a_p1 + kt * 32, &lAf[buf][as1 * 4]);
        gll16f(a_p2 + kt * 32, &lAf[buf][as2 * 4]);
        gll16f(a_p3 + kt * 32, &lAf[buf][as3 * 4]);
        gll16(b_p0 + kt * 32, &lB[buf][bs0 * 8]);
        gll16(b_p1 + kt * 32, &lB[buf][bs1 * 8]);
    };

    stage(0, 0);
    int buf = 0;
    #pragma unroll 1
    for (int kt = 0; kt < 32; ++kt) {
        __syncthreads();                 // drains stage(kt)
        if (kt + 1 < 32) stage(buf ^ 1, kt + 1);
        bf16x8 af[4], bfr[4];
        #pragma unroll
        for (int i = 0; i < 4; i++) {
            int ra = wm + i * 16 + lr;
            int e = ra & 7;
            const float* arow = &lAf[buf][ra * 32];
            f32x4 lo = *(const f32x4*)(arow + ((( lg * 2)      ^ e) * 4));
            f32x4 hi = *(const f32x4*)(arow + ((((lg * 2) + 1) ^ e) * 4));
            bf16x8 a8;
            #pragma unroll
            for (int j = 0; j < 4; j++) { a8[j] = (bf16_t)lo[j]; a8[4 + j] = (bf16_t)hi[j]; }
            af[i] = a8;
            int rb = wn + i * 16 + lr;
            bfr[i] = *(const bf16x8*)&lB[buf][rb * 32 + ((lg ^ ((rb >> 1) & 3)) * 8)];
        }
        #pragma unroll
        for (int mi = 0; mi < 4; mi++)
            #pragma unroll
            for (int ni = 0; ni < 4; ni++)
                acc[mi][ni] = __builtin_amdgcn_mfma_f32_16x16x32_bf16(af[mi], bfr[ni], acc[mi][ni], 0, 0, 0);
        buf ^= 1;
    }

    #pragma unroll
    for (int mi = 0; mi < 4; mi++) {
        int row = m0 + wm + mi * 16 + lg * 4;       // row = b*2048 + s(or kpos)
        int bb_ = row >> 11;
        int s   = row & 2047;
        #pragma unroll
        for (int ni = 0; ni < 4; ni++) {
            int col = n0 + wn + ni * 16 + lr;       // col = h*64 + d
            int hh = col >> 6, d6 = col & 63;
            float bval = bias[col];
            if (z == 0) {
                // Q pre-scaled by 0.125*log2e so attn can use exp2 directly
                size_t obase = (((size_t)bb_ * H_ + hh) * SQ_ + s) * HD_ + d6;
                #pragma unroll
                for (int r = 0; r < 4; r++)
                    out[obase + (size_t)r * HD_] =
                        (bf16_t)((acc[mi][ni][r] + bval) * (0.125f * LOG2E));
            } else if (z == 1) {
                int kt = s >> 6, kpb = s & 63;
                size_t tb = (((size_t)bb_ * H_ + hh) * 32 + kt) * 4096;
                #pragma unroll
                for (int r = 0; r < 4; r++) {
                    int kp = kpb + r;
                    out[tb + (size_t)kp * 64 + (((d6 >> 3) ^ (kp & 7)) * 8) + (d6 & 7)] =
                        (bf16_t)(acc[mi][ni][r] + bval);
                }
            } else {
                int kt = s >> 6, kpb = s & 63;
                int chunk = ((kpb >> 5) & 1) * 4 + ((kpb >> 2) & 3);
                int jb    = ((kpb >> 4) & 1) * 4;
                size_t tb = (((size_t)bb_ * H_ + hh) * 32 + kt) * 4096;
                bf16x4 o4;
                #pragma unroll
                for (int r = 0; r < 4; r++) o4[r] = (bf16_t)(acc[mi][ni][r] + bval);
                *(bf16x4*)(out + tb + (size_t)d6 * 64 + ((chunk ^ (d6 & 7)) * 8) + jb) = o4;
            }
        }
    }
}

// ---------------------------------------------------------------------------
// O projection: tmp(bf16) = ctx(bf16) @ Wo^T + bo + resid(fp32).
__global__ __launch_bounds__(256) void gemm_out(
    const bf16_t* __restrict__ A, const bf16_t* __restrict__ Bm,
    const float* __restrict__ bias, const float* __restrict__ resid,
    bf16_t* __restrict__ out)
{
    __shared__ __align__(16) bf16_t lA[2][4096];
    __shared__ __align__(16) bf16_t lB[2][4096];

    int tid = threadIdx.x;
    int w = tid >> 6, l = tid & 63, lr = l & 15, lg = l >> 4;
    int m0 = blockIdx.x * 128, n0 = blockIdx.y * 128;
    int wm = (w >> 1) * 64, wn = (w & 1) * 64;

    f32x4 zero4 = {0.f, 0.f, 0.f, 0.f};
    f32x4 acc[4][4];
    #pragma unroll
    for (int i = 0; i < 4; i++)
        #pragma unroll
        for (int j = 0; j < 4; j++) acc[i][j] = zero4;

    int s0 = tid, s1 = 256 + tid;
    int r0 = s0 >> 2, c0 = s0 & 3, r1 = s1 >> 2, c1 = s1 & 3;
    const bf16_t* a0 = A + (size_t)(m0 + r0) * 1024 + ((c0 ^ ((r0 >> 1) & 3)) * 8);
    const bf16_t* a1 = A + (size_t)(m0 + r1) * 1024 + ((c1 ^ ((r1 >> 1) & 3)) * 8);
    const bf16_t* b0 = Bm + (size_t)(n0 + r0) * 1024 + ((c0 ^ ((r0 >> 1) & 3)) * 8);
    const bf16_t* b1 = Bm + (size_t)(n0 + r1) * 1024 + ((c1 ^ ((r1 >> 1) & 3)) * 8);

    auto stage = [&](int buf, int kt) {
        gll16(a0 + kt * 32, &lA[buf][s0 * 8]);
        gll16(a1 + kt * 32, &lA[buf][s1 * 8]);
        gll16(b0 + kt * 32, &lB[buf][s0 * 8]);
        gll16(b1 + kt * 32, &lB[buf][s1 * 8]);
    };

    stage(0, 0);
    int buf = 0;
    #pragma unroll 1
    for (int kt = 0; kt < 32; ++kt) {
        __syncthreads();
        if (kt + 1 < 32) stage(buf ^ 1, kt + 1);
        bf16x8 af[4], bfr[4];
        #pragma unroll
        for (int i = 0; i < 4; i++) {
            int ra = wm + i * 16 + lr;
            af[i] = *(const bf16x8*)&lA[buf][ra * 32 + ((lg ^ ((ra >> 1) & 3)) * 8)];
            int rb = wn + i * 16 + lr;
            bfr[i] = *(const bf16x8*)&lB[buf][rb * 32 + ((lg ^ ((rb >> 1) & 3)) * 8)];
        }
        #pragma unroll
        for (int mi = 0; mi < 4; mi++)
            #pragma unroll
            for (int ni = 0; ni < 4; ni++)
                acc[mi][ni] = __builtin_amdgcn_mfma_f32_16x16x32_bf16(af[mi], bfr[ni], acc[mi][ni], 0, 0, 0);
        buf ^= 1;
    }

    #pragma unroll
    for (int mi = 0; mi < 4; mi++) {
        int row = m0 + wm + mi * 16 + lg * 4;
        #pragma unroll
        for (int ni = 0; ni < 4; ni++) {
            int col = n0 + wn + ni * 16 + lr;
            float bval = bias[col];
            #pragma unroll
            for (int r = 0; r < 4; r++) {
                size_t o = (size_t)(row + r) * D_ + col;
                out[o] = (bf16_t)(acc[mi][ni][r] + bval + resid[o]);
            }
        }
    }
}

// ---------------------------------------------------------------------------
// Flash attention: (b,h,qt-of-128) per block, 8 THIN waves x 16 q-rows each
// (one q-set per wave; r16 had 4 fat waves x 2 sets). Same LDS (66 KB), same
// KBLK=128 pair staging, same blocks -> resident waves/SIMD double (2->4),
// per-wave serial chain halves. Body: ones-trick denominator, raw v_exp_f32.
__global__ __launch_bounds__(512) void attn_kernel(
    const bf16_t* __restrict__ qg, const bf16_t* __restrict__ kgt,
    const bf16_t* __restrict__ vgt, const float* __restrict__ bias,
    const int* __restrict__ mask, bf16_t* __restrict__ ctx)
{
    __shared__ __align__(16) bf16_t ksh[2][8192];   // pair of 64x64 tiles
    __shared__ __align__(16) bf16_t vsh[2][8192];
    __shared__ __align__(8) unsigned char mlds[256];   // 2048 mask bits

    // Swizzle: the 4 batch-siblings of one (h,qt) share x mod 8 -> same XCD L2
    int x = blockIdx.x;              // 1024 blocks
    int g8 = x & 7;
    int rest = x >> 3;               // 0..127
    int b  = rest & 3;
    int tt = ((rest >> 2) << 3) | g8;   // 0..255
    int h  = tt >> 4;
    int qt = tt & 15;

    int tid = threadIdx.x;           // 0..511
    int w   = tid >> 6;              // 0..7
    int l   = tid & 63;
    int q16 = l & 15;
    int g   = l >> 4;
    int g4  = g * 4;

    int qrow = qt * 128 + w * 16 + q16;
    const bf16_t* qbase = qg + ((size_t)b * H_ + h) * SQ_ * HD_;
    bf16x8 qf0 = *(const bf16x8*)(qbase + (size_t)qrow * HD_ + g * 8);
    bf16x8 qf1 = *(const bf16x8*)(qbase + (size_t)qrow * HD_ + 32 + g * 8);

    const bf16_t* kt_base = kgt + ((size_t)b * H_ + h) * 32 * 4096;
    const bf16_t* vt_base = vgt + ((size_t)b * H_ + h) * 32 * 4096;
    const float* bias_row = bias + ((size_t)h * SQ_ + qrow) * SK_;

    f32x4 zero4 = {0.f, 0.f, 0.f, 0.f};
    f32x4 oacc[4];
    #pragma unroll
    for (int i = 0; i < 4; i++) oacc[i] = zero4;
    f32x4 lacc = zero4;              // ones-trick denominator accumulator

    bf16x8 ones;
    #pragma unroll
    for (int i = 0; i < 8; i++) ones[i] = (bf16_t)1.0f;

    // stage a PAIR of tiles (16 KB K + 16 KB V): 4 gll16 per thread @512
    auto stagePair = [&](int buf, int pt) {
        const bf16_t* ks = kt_base + (size_t)pt * 8192 + tid * 8;
        const bf16_t* vs = vt_base + (size_t)pt * 8192 + tid * 8;
        #pragma unroll
        for (int c = 0; c < 2; c++) {
            gll16(ks + c * 4096, &ksh[buf][c * 4096 + tid * 8]);
            gll16(vs + c * 4096, &vsh[buf][c * 4096 + tid * 8]);
        }
    };

    auto body = [&](const bf16_t* kb, const bf16_t* vb, int t) {
        // ---- bias + mask issued early (latency hides under QK^T) ----
        f32x4 bb[4];
        const float* bp = bias_row + t * 64 + g4;
        #pragma unroll
        for (int ni = 0; ni < 4; ni++) bb[ni] = *(const f32x4*)(bp + ni * 16);
        u32x2 mm = *(const u32x2*)&mlds[t * 8];
        unsigned lo = mm[0], hi = mm[1];

        // ---- S^T = K Q^T ----
        f32x4 s0[4];
        __builtin_amdgcn_s_setprio(1);
        #pragma unroll
        for (int ni = 0; ni < 4; ni++) {
            int krow = ni * 16 + q16;
            const bf16_t* kr = kb + krow * 64;
            bf16x8 kf0 = *(const bf16x8*)(kr + ((g       ^ (krow & 7)) * 8));
            bf16x8 kf1 = *(const bf16x8*)(kr + (((4 + g) ^ (krow & 7)) * 8));
            s0[ni] = zero4;
            s0[ni] = __builtin_amdgcn_mfma_f32_16x16x32_bf16(kf0, qf0, s0[ni], 0, 0, 0);
            s0[ni] = __builtin_amdgcn_mfma_f32_16x16x32_bf16(kf1, qf1, s0[ni], 0, 0, 0);
        }
        __builtin_amdgcn_s_setprio(0);

        unsigned n0_ = (lo >> g4) & 0xF;
        unsigned n1_ = (lo >> (16 + g4)) & 0xF;
        unsigned n2_ = (hi >> g4) & 0xF;
        unsigned n3_ = (hi >> (16 + g4)) & 0xF;

        bf16x8 pA0, pA1;
        #pragma unroll
        for (int r = 0; r < 4; r++) {
            float b0 = ((n0_ >> r) & 1) ? bb[0][r] : -30000.f;
            float b1 = ((n1_ >> r) & 1) ? bb[1][r] : -30000.f;
            float b2 = ((n2_ >> r) & 1) ? bb[2][r] : -30000.f;
            float b3 = ((n3_ >> r) & 1) ? bb[3][r] : -30000.f;
            pA0[r]     = (bf16_t)__builtin_amdgcn_exp2f(fmaf(b0, LOG2E, s0[0][r]));
            pA0[4 + r] = (bf16_t)__builtin_amdgcn_exp2f(fmaf(b1, LOG2E, s0[1][r]));
            pA1[r]     = (bf16_t)__builtin_amdgcn_exp2f(fmaf(b2, LOG2E, s0[2][r]));
            pA1[4 + r] = (bf16_t)__builtin_amdgcn_exp2f(fmaf(b3, LOG2E, s0[3][r]));
        }

        // ---- O^T += V^T P, denominator += ones^T P (colsum) ----
        __builtin_amdgcn_s_setprio(1);
        lacc = __builtin_amdgcn_mfma_f32_16x16x32_bf16(ones, pA0, lacc, 0, 0, 0);
        lacc = __builtin_amdgcn_mfma_f32_16x16x32_bf16(ones, pA1, lacc, 0, 0, 0);
        #pragma unroll
        for (int nd = 0; nd < 4; nd++) {
            int vrow = nd * 16 + q16;
            const bf16_t* vr = vb + vrow * 64;
            bf16x8 vf0 = *(const bf16x8*)(vr + ((g       ^ (vrow & 7)) * 8));
            bf16x8 vf1 = *(const bf16x8*)(vr + (((4 + g) ^ (vrow & 7)) * 8));
            oacc[nd] = __builtin_amdgcn_mfma_f32_16x16x32_bf16(vf0, pA0, oacc[nd], 0, 0, 0);
            oacc[nd] = __builtin_amdgcn_mfma_f32_16x16x32_bf16(vf1, pA1, oacc[nd], 0, 0, 0);
        }
        __builtin_amdgcn_s_setprio(0);
    };

    // ---- prologue ----
    stagePair(0, 0);
    if (tid < 256) {
        const int* mp = mask + (size_t)b * SK_ + tid * 8;
        i32x4 u0 = *(const i32x4*)mp;
        i32x4 u1 = *(const i32x4*)(mp + 4);
        unsigned by = 0;
        #pragma unroll
        for (int j = 0; j < 4; j++) by |= (u0[j] != 0 ? 1u : 0u) << j;
        #pragma unroll
        for (int j = 0; j < 4; j++) by |= (u1[j] != 0 ? 1u : 0u) << (4 + j);
        mlds[tid] = (unsigned char)by;
    }
    __syncthreads();     // mlds visible; pair 0 staged

    #pragma unroll 1
    for (int pt = 0; pt < 16; ++pt) {
        int buf = pt & 1;
        // stage next pair FIRST: two bodies of cover before the barrier drain
        if (pt + 1 < 16) stagePair(buf ^ 1, pt + 1);
        body(&ksh[buf][0],    &vsh[buf][0],    2 * pt);
        body(&ksh[buf][4096], &vsh[buf][4096], 2 * pt + 1);
        // single barrier per PAIR: drains stagePair(pt+1), resolves WAR
        __syncthreads();
    }

    // ---- denominator: lacc[m][q16] = colsum P, identical across m ----
    float l_r = lacc[0];
    float inv = (l_r > 0.f) ? 1.0f / l_r : 0.f;

    bf16_t* cp = ctx + ((size_t)b * SQ_ + qrow) * D_ + (size_t)h * HD_;
    #pragma unroll
    for (int nd = 0; nd < 4; nd++) {
        bf16x4 o4;
        #pragma unroll
        for (int r = 0; r < 4; r++) o4[r] = (bf16_t)(oacc[nd][r] * inv);
        *(bf16x4*)(cp + nd * 16 + g4) = o4;
    }
}

// ---------------------------------------------------------------------------
// LayerNorm over D=1024, one block (256 threads) per row; x in bf16, out fp32
__global__ __launch_bounds__(256) void ln_kernel(
    const bf16_t* __restrict__ x, const float* __restrict__ gamma,
    const float* __restrict__ beta, float* __restrict__ out)
{
    int row = blockIdx.x;
    int t = threadIdx.x;
    const bf16_t* src = x + (size_t)row * D_;
    bf16x4 v4 = *(const bf16x4*)(src + t * 4);
    f32x4 v;
    #pragma unroll
    for (int i = 0; i < 4; i++) v[i] = (float)v4[i];
    float s  = v[0] + v[1] + v[2] + v[3];
    float s2 = v[0] * v[0] + v[1] * v[1] + v[2] * v[2] + v[3] * v[3];
    #pragma unroll
    for (int off = 32; off > 0; off >>= 1) {
        s  += __shfl_down(s, off);
        s2 += __shfl_down(s2, off);
    }
    __shared__ float red[8];
    int w = t >> 6, l = t & 63;
    if (l == 0) { red[w] = s; red[4 + w] = s2; }
    __syncthreads();
    if (t == 0) {
        red[0] = red[0] + red[1] + red[2] + red[3];
        red[4] = red[4] + red[5] + red[6] + red[7];
    }
    __syncthreads();
    float mu  = red[0] * (1.0f / D_);
    float var = red[4] * (1.0f / D_) - mu * mu;
    float rstd = rsqrtf(var + 1e-5f);
    f32x4 g  = *(const f32x4*)(gamma + t * 4);
    f32x4 be = *(const f32x4*)(beta + t * 4);
    f32x4 o;
    #pragma unroll
    for (int i = 0; i < 4; i++) o[i] = (v[i] - mu) * rstd * g[i] + be[i];
    *(f32x4*)(out + (size_t)row * D_ + t * 4) = o;
}

// ---------------------------------------------------------------------------
extern "C" void kernel_launch(void* const* d_in, const int* in_sizes, int n_in,
                              void* d_out, int out_size, void* d_ws, size_t ws_size,
                              hipStream_t stream)
{
    const float* query = (const float*)d_in[0];
    const float* key   = (const float*)d_in[1];
    const float* value = (const float*)d_in[2];
    const int*   mask  = (const int*)d_in[3];
    const float* bias  = (const float*)d_in[4];
    const float* Wq    = (const float*)d_in[5];
    const float* bq    = (const float*)d_in[6];
    const float* Wk    = (const float*)d_in[7];
    const float* bk    = (const float*)d_in[8];
    const float* Wv    = (const float*)d_in[9];
    const float* bv    = (const float*)d_in[10];
    const float* Wo    = (const float*)d_in[11];
    const float* bo    = (const float*)d_in[12];
    const float* gamma = (const float*)d_in[13];
    const float* beta  = (const float*)d_in[14];
    float* out = (float*)d_out;

    char* ws = (char*)d_ws;
    const size_t MB = 1024 * 1024;
    // layout (104 MB):
    //   0..16   ctx (attn out, bf16 [B,SQ,D])
    //   16..32  tmp (gemm_out bf16 x = ctx@Wo+bo+resid)
    //   48..56  wb (bf16 Wq,Wk,Wv,Wo)
    //   56..72  qb ; 72..88 kgt ; 88..104 vgt
    bf16_t* ctx = (bf16_t*)(ws);
    bf16_t* tmp = (bf16_t*)(ws + 16 * MB);
    bf16_t* wb  = (bf16_t*)(ws + 48 * MB);
    bf16_t* qb  = (bf16_t*)(ws + 56 * MB);
    bf16_t* kgt = (bf16_t*)(ws + 72 * MB);
    bf16_t* vgt = (bf16_t*)(ws + 88 * MB);

    cvt_bf16<<<dim3(512, 4), 256, 0, stream>>>(Wq, Wk, Wv, Wo, wb, 1024 * 1024);
    gemm_qkv<<<dim3(64, 8, 3), 256, 0, stream>>>(query, key, value, wb,
                                                 bq, bk, bv, qb, kgt, vgt);
    attn_kernel<<<dim3(1024), 512, 0, stream>>>(qb, kgt, vgt, bias, mask, ctx);
    gemm_out<<<dim3(64, 8), 256, 0, stream>>>(ctx, wb + (size_t)3 * 1024 * 1024, bo, query, tmp);
    ln_kernel<<<dim3(8192), 256, 0, stream>>>(tmp, gamma, beta, out);
}